// Round 6
// baseline (602.050 us; speedup 1.0000x reference)
//
#include <hip/hip_runtime.h>

// ---------------------------------------------------------------------------
// CA2_82300163326041: dual cross-attention fusion, MI355X bf16-MFMA pipeline.
//   k1 q_gemm  : Qcat[16384,1024](bf16) = [X|Y] @ [W_xq|W_yq]^T + bias
//   k2 kv_gemm : Kf[16384,512](bf16), Vt[8][512][2048](bf16 transposed V_f)
//   k3 attn    : flash-style, WG = 64 q-rows x 4 waves, ONE barrier/iter,
//                QK(kb)+PV(prev kb) pipelined. XCD swizzle (wgid&7=batch:
//                each XCD's K/V working set = 4MB = its L2) + STAGGERED
//                key-block start (start = qx*2+w, distinct per block on an
//                XCD) so barrier-locked blocks never burst the same L2
//                lines in the same iteration (round-3 lesson: lockstep
//                same-address bursts serialize on L2 channels).
//                Key-order commutative: static-max softmax, plain sums.
//   k4 add     : out = X + Y + attn0 + attn1   (fp32)
// MFMA layouts (measured, guide §3): A[m=lane&15][k=quad*8+j],
// Bt[n=lane&15][k=quad*8+j], D: col=lane&15, row=quad*4+reg.
// ---------------------------------------------------------------------------

#define B_    8
#define S_    2048
#define D_    512
#define M_TOT (B_ * S_) /* 16384 */

typedef __bf16 bf16_t;
typedef __bf16 bf16x8 __attribute__((ext_vector_type(8)));
typedef __bf16 bf16x4 __attribute__((ext_vector_type(4)));
typedef float  f32x4  __attribute__((ext_vector_type(4)));

typedef __attribute__((address_space(1))) const void* gas_cv;
typedef __attribute__((address_space(3))) void*       las_v;

__device__ __forceinline__ f32x4 mfma16(bf16x8 a, bf16x8 b, f32x4 c) {
    return __builtin_amdgcn_mfma_f32_16x16x32_bf16(a, b, c, 0, 0, 0);
}
__device__ __forceinline__ void load_lds16(const void* g, void* l) {
    __builtin_amdgcn_global_load_lds((gas_cv)g, (las_v)l, 16, 0, 0);
}

// ---------------------------------------------------------------------------
// k1: Qcat = [X|Y] @ [W_xq|W_yq]^T + bias. 128x128 tile, BK=32, fp32->bf16
// conversion during LDS staging. (round-1 proven version)
// ---------------------------------------------------------------------------
__global__ __launch_bounds__(256) void k_qgemm(
    const float* __restrict__ X, const float* __restrict__ Y,
    const float* __restrict__ Wxq, const float* __restrict__ bxq,
    const float* __restrict__ Wyq, const float* __restrict__ byq,
    bf16_t* __restrict__ Qcat)
{
    __shared__ __attribute__((aligned(16))) bf16_t Al[128 * 40];
    __shared__ __attribute__((aligned(16))) bf16_t Bl[128 * 40];
    const int m0 = blockIdx.x * 128;
    const int n0 = blockIdx.y * 128;
    const bool second = (n0 >= 512);
    const float* A    = second ? Y : X;
    const float* W    = second ? Wyq : Wxq;
    const float* bias = second ? byq : bxq;
    const int nw = n0 & 511;
    const int t    = threadIdx.x;
    const int lane = t & 63;
    const int wv   = t >> 6;
    const int wm   = (wv & 1) * 64;
    const int wn   = (wv >> 1) * 64;
    const int l15  = lane & 15;
    const int quad = lane >> 4;

    f32x4 acc[4][4] = {};

    for (int k0 = 0; k0 < 512; k0 += 32) {
        __syncthreads();
#pragma unroll
        for (int p = 0; p < 4; ++p) {
            const int lin = p * 256 + t;
            const int row = lin >> 3;
            const int ch  = (lin & 7) * 4;
            const float4 va = *(const float4*)(A + (size_t)(m0 + row) * 512 + k0 + ch);
            bf16x4 pa = { (bf16_t)va.x, (bf16_t)va.y, (bf16_t)va.z, (bf16_t)va.w };
            *(bf16x4*)(Al + row * 40 + ch) = pa;
            const float4 vb = *(const float4*)(W + (size_t)(nw + row) * 512 + k0 + ch);
            bf16x4 pb = { (bf16_t)vb.x, (bf16_t)vb.y, (bf16_t)vb.z, (bf16_t)vb.w };
            *(bf16x4*)(Bl + row * 40 + ch) = pb;
        }
        __syncthreads();
        bf16x8 af[4], bfr[4];
#pragma unroll
        for (int i = 0; i < 4; ++i)
            af[i] = *(const bf16x8*)(Al + (wm + i * 16 + l15) * 40 + quad * 8);
#pragma unroll
        for (int i = 0; i < 4; ++i)
            bfr[i] = *(const bf16x8*)(Bl + (wn + i * 16 + l15) * 40 + quad * 8);
#pragma unroll
        for (int mt = 0; mt < 4; ++mt)
#pragma unroll
            for (int nt = 0; nt < 4; ++nt)
                acc[mt][nt] = mfma16(af[mt], bfr[nt], acc[mt][nt]);
    }

#pragma unroll
    for (int nt = 0; nt < 4; ++nt) {
        const int col  = n0 + wn + nt * 16 + l15;
        const float bv = bias[col & 511];
#pragma unroll
        for (int mt = 0; mt < 4; ++mt) {
            const int rowb = m0 + wm + mt * 16 + quad * 4;
#pragma unroll
            for (int r = 0; r < 4; ++r)
                Qcat[(size_t)(rowb + r) * 1024 + col] = (bf16_t)(acc[mt][nt][r] + bv);
        }
    }
}

// ---------------------------------------------------------------------------
// k2: [Kf | Vf] = Qcat @ [W_fk | W_fv]^T + bias.  K=1024.  Kf row-major.
// A-side (bf16 Qcat) DMA-staged into linear [128][32]; W fp32 reg-staged.
// Vf stored TRANSPOSED per batch Vt[b][d][s] via LDS transpose (union).
// ---------------------------------------------------------------------------
__global__ __launch_bounds__(256) void k_kvgemm(
    const bf16_t* __restrict__ Qcat,
    const float* __restrict__ Wfk, const float* __restrict__ bfk,
    const float* __restrict__ Wfv, const float* __restrict__ bfv,
    bf16_t* __restrict__ Kf, bf16_t* __restrict__ Vt)
{
    __shared__ __attribute__((aligned(16))) union {
        struct { bf16_t Al[128 * 32]; bf16_t Bl[128 * 32]; } g;
        bf16_t T[128 * 132];   // [d_local][s_local], pad 128->132
    } sm;
    const int m0 = blockIdx.x * 128;
    const int n0 = blockIdx.y * 128;
    const bool isV = (n0 >= 512);
    const float* W    = isV ? Wfv : Wfk;
    const float* bias = isV ? bfv : bfk;
    const int nw = n0 & 511;
    const int t    = threadIdx.x;
    const int lane = t & 63;
    const int wv   = t >> 6;
    const int wm   = (wv & 1) * 64;
    const int wn   = (wv >> 1) * 64;
    const int l15  = lane & 15;
    const int quad = lane >> 4;

    const int ar0 = t >> 2,          ac0 = (t & 3) * 8;
    const int ar1 = (256 + t) >> 2,  ac1 = ((256 + t) & 3) * 8;

    f32x4 acc[4][4] = {};

    for (int k0 = 0; k0 < 1024; k0 += 32) {
        __syncthreads();
        load_lds16(Qcat + (size_t)(m0 + ar0) * 1024 + k0 + ac0, sm.g.Al + t * 8);
        load_lds16(Qcat + (size_t)(m0 + ar1) * 1024 + k0 + ac1, sm.g.Al + (256 + t) * 8);
#pragma unroll
        for (int p = 0; p < 4; ++p) {
            const int lin = p * 256 + t;
            const int row = lin >> 3;
            const int ch  = (lin & 7) * 4;
            const float4 vb = *(const float4*)(W + (size_t)(nw + row) * 1024 + k0 + ch);
            bf16x4 pb = { (bf16_t)vb.x, (bf16_t)vb.y, (bf16_t)vb.z, (bf16_t)vb.w };
            *(bf16x4*)(sm.g.Bl + row * 32 + ch) = pb;
        }
        __syncthreads();
        bf16x8 af[4], bfr[4];
#pragma unroll
        for (int i = 0; i < 4; ++i)
            af[i] = *(const bf16x8*)(sm.g.Al + (wm + i * 16 + l15) * 32 + quad * 8);
#pragma unroll
        for (int i = 0; i < 4; ++i)
            bfr[i] = *(const bf16x8*)(sm.g.Bl + (wn + i * 16 + l15) * 32 + quad * 8);
#pragma unroll
        for (int mt = 0; mt < 4; ++mt)
#pragma unroll
            for (int nt = 0; nt < 4; ++nt)
                acc[mt][nt] = mfma16(af[mt], bfr[nt], acc[mt][nt]);
    }

    if (!isV) {
#pragma unroll
        for (int nt = 0; nt < 4; ++nt) {
            const int col  = n0 + wn + nt * 16 + l15;   // < 512
            const float bv = bias[col];
#pragma unroll
            for (int mt = 0; mt < 4; ++mt) {
                const int rowb = m0 + wm + mt * 16 + quad * 4;
#pragma unroll
                for (int r = 0; r < 4; ++r)
                    Kf[(size_t)(rowb + r) * 512 + col] = (bf16_t)(acc[mt][nt][r] + bv);
            }
        }
    } else {
        __syncthreads();   // staging reads of the last k-block are done
#pragma unroll
        for (int nt = 0; nt < 4; ++nt) {
            const int dl = wn + nt * 16 + l15;
            const float bv = bias[nw + dl];
#pragma unroll
            for (int mt = 0; mt < 4; ++mt) {
                const int sl = wm + mt * 16 + quad * 4;
#pragma unroll
                for (int r = 0; r < 4; ++r)
                    sm.T[dl * 132 + sl + r] = (bf16_t)(acc[mt][nt][r] + bv);
            }
        }
        __syncthreads();
        const int bb = m0 >> 11;             // batch
        const int sb = m0 & 2047;
        const int half = lane >> 5;
        const int sl4  = (lane & 31) * 4;
#pragma unroll
        for (int i = 0; i < 16; ++i) {
            const int dl = wv * 32 + i * 2 + half;
            const bf16x4 v = *(const bf16x4*)(sm.T + dl * 132 + sl4);
            *(bf16x4*)(Vt + (size_t)(bb * 512 + nw + dl) * 2048 + sb + sl4) = v;
        }
    }
}

// ---------------------------------------------------------------------------
// k3: attention. XCD swizzle (wgid&7=b) + staggered key-block start:
//   start = (qx*2 + w) & 63 — all 64 blocks on an XCD visit distinct
//   key-blocks at any instant; K/V stay L2-resident but no same-line bursts.
//   Visit order: kb(i) = (start+i) & 63, i = 0..63. Sums are commutative.
// ---------------------------------------------------------------------------
__global__ __launch_bounds__(256, 2) void k_attn(
    const bf16_t* __restrict__ Qcat, const bf16_t* __restrict__ Kf,
    const bf16_t* __restrict__ Vt,
    const float* __restrict__ X, const float* __restrict__ Y,
    float* __restrict__ out, bf16_t* __restrict__ attn,
    const int mode, const int which)
{
    __shared__ __attribute__((aligned(16))) bf16_t Kl[2][32 * 520];
    __shared__ __attribute__((aligned(16))) bf16_t Pl[2][64 * 40];
    __shared__ float lsumL[64];

    const int wgid = blockIdx.x;
    const int b  = wgid & 7;
    const int qx = (wgid >> 3) & 31;
    const int w  = (mode == 0) ? (wgid >> 8) : which;
    const int start = (qx * 2 + w) & 63;     // de-phased key-block start
    const int t    = threadIdx.x;
    const int lane = t & 63;
    const int wv   = t >> 6;
    const int l15  = lane & 15;
    const int quad = lane >> 4;
    const int q0   = qx * 64;                // WG q-tile base
    const int qw   = q0 + wv * 16;           // this wave's QK rows

    const bf16_t* Kbase = Kf + (size_t)b * S_ * 512;
    const bf16_t* Vbase = Vt + ((size_t)b * 512 + wv * 128) * S_;

    // Q fragments: A[m=l15][k=quad*8+j], rows qw..qw+15, full K=512
    bf16x8 aq[16];
    {
        const bf16_t* qp = Qcat + (size_t)(b * S_ + qw + l15) * 1024 + w * 512 + quad * 8;
#pragma unroll
        for (int ks = 0; ks < 16; ++ks) aq[ks] = *(const bf16x8*)(qp + ks * 32);
    }

    f32x4 acc[4][8] = {};   // O[q = qt*16+quad*4+r][d = wv*128+dt*16+l15]
    float lacc[4] = { 0.f, 0.f, 0.f, 0.f };   // per-lane partial row sums
    // exp2 domain: 1/sqrt(512) * log2(e)
    const float sc2 = 0.04419417382415922f * 1.4426950408889634f;

    // ---- prologue: K(start) -> Kl[0]
#pragma unroll
    for (int p = 0; p < 8; ++p) {
        const int row = wv * 8 + p;
        load_lds16(Kbase + (size_t)(start * 32 + row) * 512 + lane * 8, Kl[0] + row * 520);
    }
    __syncthreads();

    // ---- peeled iter i=0 (kb=start): DMA K(start+1) -> Kl[1]; QK; exp; bar
    {
        const int kn = (start + 1) & 63;
#pragma unroll
        for (int p = 0; p < 8; ++p) {
            const int row = wv * 8 + p;
            load_lds16(Kbase + (size_t)(kn * 32 + row) * 512 + lane * 8, Kl[1] + row * 520);
        }
        f32x4 s0a = {}, s0b = {}, s1a = {}, s1b = {};
#pragma unroll
        for (int ks = 0; ks < 16; ks += 2) {
            const bf16x8 b0 = *(const bf16x8*)(Kl[0] + l15 * 520 + ks * 32 + quad * 8);
            const bf16x8 b1 = *(const bf16x8*)(Kl[0] + (16 + l15) * 520 + ks * 32 + quad * 8);
            const bf16x8 c0 = *(const bf16x8*)(Kl[0] + l15 * 520 + (ks + 1) * 32 + quad * 8);
            const bf16x8 c1 = *(const bf16x8*)(Kl[0] + (16 + l15) * 520 + (ks + 1) * 32 + quad * 8);
            s0a = mfma16(aq[ks], b0, s0a);
            s1a = mfma16(aq[ks], b1, s1a);
            s0b = mfma16(aq[ks + 1], c0, s0b);
            s1b = mfma16(aq[ks + 1], c1, s1b);
        }
        const f32x4 sA = s0a + s0b, sB = s1a + s1b;
#pragma unroll
        for (int r = 0; r < 4; ++r) {
            const float p0 = exp2f(sA[r] * sc2);
            const float p1 = exp2f(sB[r] * sc2);
            lacc[r] += p0 + p1;
            Pl[0][(wv * 16 + quad * 4 + r) * 40 + l15] = (bf16_t)p0;
            Pl[0][(wv * 16 + quad * 4 + r) * 40 + 16 + l15] = (bf16_t)p1;
        }
        __syncthreads();
    }

    // ---- main loop i = 1..63: kb=(start+i)&63; at i=63 the DMA reloads
    //      K(start) into the dead buffer — valid memory, never read.
    for (int i = 1; i < 64; ++i) {
        const int cur = i & 1;
        const int prv = cur ^ 1;
        const int kb  = (start + i) & 63;
        const int kn  = (start + i + 1) & 63;   // next to prefetch
        const int kv  = (start + i - 1) & 63;   // PV's key-block

        // stage K(kn) into Kl[prv] (drained at this iter's barrier)
        {
            const bf16_t* src = Kbase + (size_t)kn * 32 * 512;
#pragma unroll
            for (int p = 0; p < 8; ++p) {
                const int row = wv * 8 + p;
                load_lds16(src + (size_t)row * 512 + lane * 8, Kl[prv] + row * 520);
            }
        }

        // V fragments for PV(kv): Bt[n=d][k=key] from Vt (L2-resident)
        bf16x8 vb[8];
#pragma unroll
        for (int i2 = 0; i2 < 8; ++i2)
            vb[i2] = *(const bf16x8*)(Vbase + (size_t)(i2 * 16 + l15) * S_ +
                                      kv * 32 + quad * 8);

        // QK(kb): 4 independent 8-deep chains
        f32x4 s0a = {}, s0b = {}, s1a = {}, s1b = {};
#pragma unroll
        for (int ks = 0; ks < 16; ks += 2) {
            const bf16x8 b0 = *(const bf16x8*)(Kl[cur] + l15 * 520 + ks * 32 + quad * 8);
            const bf16x8 b1 = *(const bf16x8*)(Kl[cur] + (16 + l15) * 520 + ks * 32 + quad * 8);
            const bf16x8 c0 = *(const bf16x8*)(Kl[cur] + l15 * 520 + (ks + 1) * 32 + quad * 8);
            const bf16x8 c1 = *(const bf16x8*)(Kl[cur] + (16 + l15) * 520 + (ks + 1) * 32 + quad * 8);
            s0a = mfma16(aq[ks], b0, s0a);
            s1a = mfma16(aq[ks], b1, s1a);
            s0b = mfma16(aq[ks + 1], c0, s0b);
            s1b = mfma16(aq[ks + 1], c1, s1b);
        }

        // PV(kv): 32 independent MFMAs — fills QK dep-stalls + exp tail
        {
            bf16x8 ap[4];
#pragma unroll
            for (int qt = 0; qt < 4; ++qt)
                ap[qt] = *(const bf16x8*)(Pl[prv] + (qt * 16 + l15) * 40 + quad * 8);
#pragma unroll
            for (int dt = 0; dt < 8; ++dt)
#pragma unroll
                for (int qt = 0; qt < 4; ++qt)
                    acc[qt][dt] = mfma16(ap[qt], vb[dt], acc[qt][dt]);
        }

        // exp(kb) -> Pl[cur]
        const f32x4 sA = s0a + s0b, sB = s1a + s1b;
#pragma unroll
        for (int r = 0; r < 4; ++r) {
            const float p0 = exp2f(sA[r] * sc2);
            const float p1 = exp2f(sB[r] * sc2);
            lacc[r] += p0 + p1;
            Pl[cur][(wv * 16 + quad * 4 + r) * 40 + l15] = (bf16_t)p0;
            Pl[cur][(wv * 16 + quad * 4 + r) * 40 + 16 + l15] = (bf16_t)p1;
        }

        __syncthreads();
    }

    // ---- epilogue: PV of the last visited block, from Pl[1]
    {
        const int kv = (start + 63) & 63;
        bf16x8 vb[8];
#pragma unroll
        for (int i2 = 0; i2 < 8; ++i2)
            vb[i2] = *(const bf16x8*)(Vbase + (size_t)(i2 * 16 + l15) * S_ +
                                      kv * 32 + quad * 8);
        bf16x8 ap[4];
#pragma unroll
        for (int qt = 0; qt < 4; ++qt)
            ap[qt] = *(const bf16x8*)(Pl[1] + (qt * 16 + l15) * 40 + quad * 8);
#pragma unroll
        for (int dt = 0; dt < 8; ++dt)
#pragma unroll
            for (int qt = 0; qt < 4; ++qt)
                acc[qt][dt] = mfma16(ap[qt], vb[dt], acc[qt][dt]);
    }

    // one-time row-sum reduction (16 lanes per quad) and publish
    {
        float lrow[4];
#pragma unroll
        for (int r = 0; r < 4; ++r) {
            float v = lacc[r];
#pragma unroll
            for (int off = 1; off < 16; off <<= 1) v += __shfl_xor(v, off, 64);
            lrow[r] = v;
        }
        if (l15 == 0) {
#pragma unroll
            for (int r = 0; r < 4; ++r) lsumL[wv * 16 + quad * 4 + r] = lrow[r];
        }
    }
    __syncthreads();

#pragma unroll
    for (int qt = 0; qt < 4; ++qt) {
        f32x4 inv;
#pragma unroll
        for (int r = 0; r < 4; ++r) inv[r] = 1.0f / lsumL[qt * 16 + quad * 4 + r];
#pragma unroll
        for (int dt = 0; dt < 8; ++dt) {
            const int d = wv * 128 + dt * 16 + l15;
#pragma unroll
            for (int r = 0; r < 4; ++r) {
                const float v = acc[qt][dt][r] * inv[r];
                const size_t idx =
                    (size_t)(b * S_ + q0 + qt * 16 + quad * 4 + r) * 512 + d;
                if (mode == 0)      attn[(size_t)w * M_TOT * 512 + idx] = (bf16_t)v;
                else if (mode == 1) out[idx] = X[idx] + Y[idx] + v;
                else                out[idx] += v;
            }
        }
    }
}

// ---------------------------------------------------------------------------
// k4: out = X + Y + attn0 + attn1
// ---------------------------------------------------------------------------
__global__ __launch_bounds__(256) void k_add(
    const float* __restrict__ X, const float* __restrict__ Y,
    const bf16_t* __restrict__ a0, const bf16_t* __restrict__ a1,
    float* __restrict__ out)
{
    const size_t i = ((size_t)blockIdx.x * 256 + threadIdx.x) * 4;
    const float4 x = *(const float4*)(X + i);
    const float4 y = *(const float4*)(Y + i);
    const bf16x4 v0 = *(const bf16x4*)(a0 + i);
    const bf16x4 v1 = *(const bf16x4*)(a1 + i);
    float4 o;
    o.x = x.x + y.x + (float)v0[0] + (float)v1[0];
    o.y = x.y + y.y + (float)v0[1] + (float)v1[1];
    o.z = x.z + y.z + (float)v0[2] + (float)v1[2];
    o.w = x.w + y.w + (float)v0[3] + (float)v1[3];
    *(float4*)(out + i) = o;
}

extern "C" void kernel_launch(void* const* d_in, const int* in_sizes, int n_in,
                              void* d_out, int out_size, void* d_ws, size_t ws_size,
                              hipStream_t stream)
{
    const float* X   = (const float*)d_in[0];
    const float* Y   = (const float*)d_in[1];
    const float* Wxq = (const float*)d_in[2];
    const float* bxq = (const float*)d_in[3];
    const float* Wyq = (const float*)d_in[4];
    const float* byq = (const float*)d_in[5];
    const float* Wfk = (const float*)d_in[6];
    const float* bfk = (const float*)d_in[7];
    const float* Wfv = (const float*)d_in[8];
    const float* bfv = (const float*)d_in[9];
    float* out = (float*)d_out;
    char*  ws  = (char*)d_ws;

    // ws layout (bytes): Qcat 32MiB | Kf 16MiB | Vt 16MiB | attn 2x16MiB
    bf16_t* Qcat = (bf16_t*)(ws);
    bf16_t* Kf   = (bf16_t*)(ws + (size_t)33554432);
    bf16_t* Vt   = (bf16_t*)(ws + (size_t)50331648);
    bf16_t* attn = (bf16_t*)(ws + (size_t)67108864);
    const bool big = ws_size >= (size_t)100663296;

    k_qgemm<<<dim3(128, 8), 256, 0, stream>>>(X, Y, Wxq, bxq, Wyq, byq, Qcat);
    k_kvgemm<<<dim3(128, 8), 256, 0, stream>>>(Qcat, Wfk, bfk, Wfv, bfv, Kf, Vt);
    if (big) {
        k_attn<<<dim3(512), 256, 0, stream>>>(Qcat, Kf, Vt, X, Y, out, attn, 0, 0);
        k_add<<<dim3(8192), 256, 0, stream>>>(X, Y, attn, attn + (size_t)M_TOT * 512, out);
    } else {
        k_attn<<<dim3(256), 256, 0, stream>>>(Qcat, Kf, Vt, X, Y, out, attn, 1, 0);
        k_attn<<<dim3(256), 256, 0, stream>>>(Qcat, Kf, Vt, X, Y, out, attn, 2, 1);
    }
}

// Round 7
// 476.543 us; speedup vs baseline: 1.2634x; 1.2634x over previous
//
#include <hip/hip_runtime.h>

// ---------------------------------------------------------------------------
// CA2_82300163326041: dual cross-attention fusion, MI355X bf16-MFMA pipeline.
//   k1 q_gemm  : Qcat[16384,1024](bf16) = [X|Y] @ [W_xq|W_yq]^T + bias
//   k2 kv_gemm : Kf[16384,512](bf16), Vt[8][512][2048](bf16 transposed V_f)
//   k3 attn    : flash-style, WG = 64 q-rows x 4 waves, ONE barrier/iter,
//                QK(kb)+PV(kb-1) pipelined. ROUND-7 CHANGE (single var):
//                V loads issued BEFORE the K-DMA, so PV's implicit wait is
//                vmcnt(8) — the next-tile K-DMA stays in flight through PV
//                and is drained only at the barrier (R1 issued DMA first,
//                forcing vmcnt(0) before PV = serialized DMA mid-iter).
//                Grid/body otherwise EXACTLY round-1 (241 µs floor).
//   k4 add     : out = X + Y + attn0 + attn1   (fp32)
// Post-mortem ledger: R2 (V-first+setprio+Pl36) FETCH x2 — blamed setprio.
// R3 lockstep XCD swizzle: FETCH 34MB but +32µs (L2 same-line bursts).
// R6 stagger: working set > L2, FETCH 380MB, +126µs. Locality program
// closed: kernel is stall-structure-bound at 10% HBM, not traffic-bound.
// ---------------------------------------------------------------------------

#define B_    8
#define S_    2048
#define D_    512
#define M_TOT (B_ * S_) /* 16384 */

typedef __bf16 bf16_t;
typedef __bf16 bf16x8 __attribute__((ext_vector_type(8)));
typedef __bf16 bf16x4 __attribute__((ext_vector_type(4)));
typedef float  f32x4  __attribute__((ext_vector_type(4)));

typedef __attribute__((address_space(1))) const void* gas_cv;
typedef __attribute__((address_space(3))) void*       las_v;

__device__ __forceinline__ f32x4 mfma16(bf16x8 a, bf16x8 b, f32x4 c) {
    return __builtin_amdgcn_mfma_f32_16x16x32_bf16(a, b, c, 0, 0, 0);
}
__device__ __forceinline__ void load_lds16(const void* g, void* l) {
    __builtin_amdgcn_global_load_lds((gas_cv)g, (las_v)l, 16, 0, 0);
}

// ---------------------------------------------------------------------------
// k1: Qcat = [X|Y] @ [W_xq|W_yq]^T + bias. 128x128 tile, BK=32, fp32->bf16
// conversion during LDS staging. (round-1 proven version)
// ---------------------------------------------------------------------------
__global__ __launch_bounds__(256) void k_qgemm(
    const float* __restrict__ X, const float* __restrict__ Y,
    const float* __restrict__ Wxq, const float* __restrict__ bxq,
    const float* __restrict__ Wyq, const float* __restrict__ byq,
    bf16_t* __restrict__ Qcat)
{
    __shared__ __attribute__((aligned(16))) bf16_t Al[128 * 40];
    __shared__ __attribute__((aligned(16))) bf16_t Bl[128 * 40];
    const int m0 = blockIdx.x * 128;
    const int n0 = blockIdx.y * 128;
    const bool second = (n0 >= 512);
    const float* A    = second ? Y : X;
    const float* W    = second ? Wyq : Wxq;
    const float* bias = second ? byq : bxq;
    const int nw = n0 & 511;
    const int t    = threadIdx.x;
    const int lane = t & 63;
    const int wv   = t >> 6;
    const int wm   = (wv & 1) * 64;
    const int wn   = (wv >> 1) * 64;
    const int l15  = lane & 15;
    const int quad = lane >> 4;

    f32x4 acc[4][4] = {};

    for (int k0 = 0; k0 < 512; k0 += 32) {
        __syncthreads();
#pragma unroll
        for (int p = 0; p < 4; ++p) {
            const int lin = p * 256 + t;
            const int row = lin >> 3;
            const int ch  = (lin & 7) * 4;
            const float4 va = *(const float4*)(A + (size_t)(m0 + row) * 512 + k0 + ch);
            bf16x4 pa = { (bf16_t)va.x, (bf16_t)va.y, (bf16_t)va.z, (bf16_t)va.w };
            *(bf16x4*)(Al + row * 40 + ch) = pa;
            const float4 vb = *(const float4*)(W + (size_t)(nw + row) * 512 + k0 + ch);
            bf16x4 pb = { (bf16_t)vb.x, (bf16_t)vb.y, (bf16_t)vb.z, (bf16_t)vb.w };
            *(bf16x4*)(Bl + row * 40 + ch) = pb;
        }
        __syncthreads();
        bf16x8 af[4], bfr[4];
#pragma unroll
        for (int i = 0; i < 4; ++i)
            af[i] = *(const bf16x8*)(Al + (wm + i * 16 + l15) * 40 + quad * 8);
#pragma unroll
        for (int i = 0; i < 4; ++i)
            bfr[i] = *(const bf16x8*)(Bl + (wn + i * 16 + l15) * 40 + quad * 8);
#pragma unroll
        for (int mt = 0; mt < 4; ++mt)
#pragma unroll
            for (int nt = 0; nt < 4; ++nt)
                acc[mt][nt] = mfma16(af[mt], bfr[nt], acc[mt][nt]);
    }

#pragma unroll
    for (int nt = 0; nt < 4; ++nt) {
        const int col  = n0 + wn + nt * 16 + l15;
        const float bv = bias[col & 511];
#pragma unroll
        for (int mt = 0; mt < 4; ++mt) {
            const int rowb = m0 + wm + mt * 16 + quad * 4;
#pragma unroll
            for (int r = 0; r < 4; ++r)
                Qcat[(size_t)(rowb + r) * 1024 + col] = (bf16_t)(acc[mt][nt][r] + bv);
        }
    }
}

// ---------------------------------------------------------------------------
// k2: [Kf | Vf] = Qcat @ [W_fk | W_fv]^T + bias.  K=1024.  Kf row-major.
// A-side (bf16 Qcat) DMA-staged into linear [128][32]; W fp32 reg-staged.
// Vf stored TRANSPOSED per batch Vt[b][d][s] via LDS transpose (union).
// ---------------------------------------------------------------------------
__global__ __launch_bounds__(256) void k_kvgemm(
    const bf16_t* __restrict__ Qcat,
    const float* __restrict__ Wfk, const float* __restrict__ bfk,
    const float* __restrict__ Wfv, const float* __restrict__ bfv,
    bf16_t* __restrict__ Kf, bf16_t* __restrict__ Vt)
{
    __shared__ __attribute__((aligned(16))) union {
        struct { bf16_t Al[128 * 32]; bf16_t Bl[128 * 32]; } g;
        bf16_t T[128 * 132];   // [d_local][s_local], pad 128->132
    } sm;
    const int m0 = blockIdx.x * 128;
    const int n0 = blockIdx.y * 128;
    const bool isV = (n0 >= 512);
    const float* W    = isV ? Wfv : Wfk;
    const float* bias = isV ? bfv : bfk;
    const int nw = n0 & 511;
    const int t    = threadIdx.x;
    const int lane = t & 63;
    const int wv   = t >> 6;
    const int wm   = (wv & 1) * 64;
    const int wn   = (wv >> 1) * 64;
    const int l15  = lane & 15;
    const int quad = lane >> 4;

    const int ar0 = t >> 2,          ac0 = (t & 3) * 8;
    const int ar1 = (256 + t) >> 2,  ac1 = ((256 + t) & 3) * 8;

    f32x4 acc[4][4] = {};

    for (int k0 = 0; k0 < 1024; k0 += 32) {
        __syncthreads();
        load_lds16(Qcat + (size_t)(m0 + ar0) * 1024 + k0 + ac0, sm.g.Al + t * 8);
        load_lds16(Qcat + (size_t)(m0 + ar1) * 1024 + k0 + ac1, sm.g.Al + (256 + t) * 8);
#pragma unroll
        for (int p = 0; p < 4; ++p) {
            const int lin = p * 256 + t;
            const int row = lin >> 3;
            const int ch  = (lin & 7) * 4;
            const float4 vb = *(const float4*)(W + (size_t)(nw + row) * 1024 + k0 + ch);
            bf16x4 pb = { (bf16_t)vb.x, (bf16_t)vb.y, (bf16_t)vb.z, (bf16_t)vb.w };
            *(bf16x4*)(sm.g.Bl + row * 32 + ch) = pb;
        }
        __syncthreads();
        bf16x8 af[4], bfr[4];
#pragma unroll
        for (int i = 0; i < 4; ++i)
            af[i] = *(const bf16x8*)(sm.g.Al + (wm + i * 16 + l15) * 32 + quad * 8);
#pragma unroll
        for (int i = 0; i < 4; ++i)
            bfr[i] = *(const bf16x8*)(sm.g.Bl + (wn + i * 16 + l15) * 32 + quad * 8);
#pragma unroll
        for (int mt = 0; mt < 4; ++mt)
#pragma unroll
            for (int nt = 0; nt < 4; ++nt)
                acc[mt][nt] = mfma16(af[mt], bfr[nt], acc[mt][nt]);
    }

    if (!isV) {
#pragma unroll
        for (int nt = 0; nt < 4; ++nt) {
            const int col  = n0 + wn + nt * 16 + l15;   // < 512
            const float bv = bias[col];
#pragma unroll
            for (int mt = 0; mt < 4; ++mt) {
                const int rowb = m0 + wm + mt * 16 + quad * 4;
#pragma unroll
                for (int r = 0; r < 4; ++r)
                    Kf[(size_t)(rowb + r) * 512 + col] = (bf16_t)(acc[mt][nt][r] + bv);
            }
        }
    } else {
        __syncthreads();   // staging reads of the last k-block are done
#pragma unroll
        for (int nt = 0; nt < 4; ++nt) {
            const int dl = wn + nt * 16 + l15;
            const float bv = bias[nw + dl];
#pragma unroll
            for (int mt = 0; mt < 4; ++mt) {
                const int sl = wm + mt * 16 + quad * 4;
#pragma unroll
                for (int r = 0; r < 4; ++r)
                    sm.T[dl * 132 + sl + r] = (bf16_t)(acc[mt][nt][r] + bv);
            }
        }
        __syncthreads();
        const int bb = m0 >> 11;             // batch
        const int sb = m0 & 2047;
        const int half = lane >> 5;
        const int sl4  = (lane & 31) * 4;
#pragma unroll
        for (int i = 0; i < 16; ++i) {
            const int dl = wv * 32 + i * 2 + half;
            const bf16x4 v = *(const bf16x4*)(sm.T + dl * 132 + sl4);
            *(bf16x4*)(Vt + (size_t)(bb * 512 + nw + dl) * 2048 + sb + sl4) = v;
        }
    }
}

// ---------------------------------------------------------------------------
// k3: attention (round-1 grid + body; ONLY change: V loads precede K-DMA in
// the main loop, so PV waits vmcnt(8) and the DMA drains at the barrier).
// ---------------------------------------------------------------------------
__global__ __launch_bounds__(256, 2) void k_attn(
    const bf16_t* __restrict__ Qcat, const bf16_t* __restrict__ Kf,
    const bf16_t* __restrict__ Vt,
    const float* __restrict__ X, const float* __restrict__ Y,
    float* __restrict__ out, bf16_t* __restrict__ attn,
    const int mode, const int which)
{
    __shared__ __attribute__((aligned(16))) bf16_t Kl[2][32 * 520];
    __shared__ __attribute__((aligned(16))) bf16_t Pl[2][64 * 40];
    __shared__ float lsumL[64];

    const int b = blockIdx.y;
    const int w = (mode == 0) ? (int)blockIdx.z : which;
    const int t    = threadIdx.x;
    const int lane = t & 63;
    const int wv   = t >> 6;
    const int l15  = lane & 15;
    const int quad = lane >> 4;
    const int q0   = blockIdx.x * 64;        // WG q-tile base
    const int qw   = q0 + wv * 16;           // this wave's QK rows

    const bf16_t* Kbase = Kf + (size_t)b * S_ * 512;
    const bf16_t* Vbase = Vt + ((size_t)b * 512 + wv * 128) * S_;

    // Q fragments: A[m=l15][k=quad*8+j], rows qw..qw+15, full K=512
    bf16x8 aq[16];
    {
        const bf16_t* qp = Qcat + (size_t)(b * S_ + qw + l15) * 1024 + w * 512 + quad * 8;
#pragma unroll
        for (int ks = 0; ks < 16; ++ks) aq[ks] = *(const bf16x8*)(qp + ks * 32);
    }

    f32x4 acc[4][8] = {};   // O[q = qt*16+quad*4+r][d = wv*128+dt*16+l15]
    float lacc[4] = { 0.f, 0.f, 0.f, 0.f };   // per-lane partial row sums
    // exp2 domain: 1/sqrt(512) * log2(e)
    const float sc2 = 0.04419417382415922f * 1.4426950408889634f;

    // ---- prologue: K0 -> Kl[0]
#pragma unroll
    for (int p = 0; p < 8; ++p) {
        const int row = wv * 8 + p;
        load_lds16(Kbase + (size_t)row * 512 + lane * 8, Kl[0] + row * 520);
    }
    __syncthreads();

    // ---- peeled iter 0: DMA K1 -> Kl[1]; QK(0); exp -> Pl[0]; barrier
    {
#pragma unroll
        for (int p = 0; p < 8; ++p) {
            const int row = wv * 8 + p;
            load_lds16(Kbase + (size_t)(32 + row) * 512 + lane * 8, Kl[1] + row * 520);
        }
        f32x4 s0a = {}, s0b = {}, s1a = {}, s1b = {};
#pragma unroll
        for (int ks = 0; ks < 16; ks += 2) {
            const bf16x8 b0 = *(const bf16x8*)(Kl[0] + l15 * 520 + ks * 32 + quad * 8);
            const bf16x8 b1 = *(const bf16x8*)(Kl[0] + (16 + l15) * 520 + ks * 32 + quad * 8);
            const bf16x8 c0 = *(const bf16x8*)(Kl[0] + l15 * 520 + (ks + 1) * 32 + quad * 8);
            const bf16x8 c1 = *(const bf16x8*)(Kl[0] + (16 + l15) * 520 + (ks + 1) * 32 + quad * 8);
            s0a = mfma16(aq[ks], b0, s0a);
            s1a = mfma16(aq[ks], b1, s1a);
            s0b = mfma16(aq[ks + 1], c0, s0b);
            s1b = mfma16(aq[ks + 1], c1, s1b);
        }
        const f32x4 sA = s0a + s0b, sB = s1a + s1b;
#pragma unroll
        for (int r = 0; r < 4; ++r) {
            const float p0 = exp2f(sA[r] * sc2);
            const float p1 = exp2f(sB[r] * sc2);
            lacc[r] += p0 + p1;
            Pl[0][(wv * 16 + quad * 4 + r) * 40 + l15] = (bf16_t)p0;
            Pl[0][(wv * 16 + quad * 4 + r) * 40 + 16 + l15] = (bf16_t)p1;
        }
        __syncthreads();
    }

    // ---- main loop kb = 1..63 (branchless; kb=63's DMA prefetches junk
    //      into the dead buffer from valid ws memory — never read)
    for (int kb = 1; kb < 64; ++kb) {
        const int cur = kb & 1;
        const int prv = cur ^ 1;

        // V fragments FIRST (oldest 8 vmem ops): PV's implicit wait becomes
        // vmcnt(8), so the K-DMA below keeps flying until the barrier.
        bf16x8 vb[8];
#pragma unroll
        for (int i = 0; i < 8; ++i)
            vb[i] = *(const bf16x8*)(Vbase + (size_t)(i * 16 + l15) * S_ +
                                     (kb - 1) * 32 + quad * 8);

        // stage K(kb+1) into Kl[prv] (drained at this iter's barrier)
        {
            const bf16_t* src = Kbase + (size_t)(kb + 1) * 32 * 512;
#pragma unroll
            for (int p = 0; p < 8; ++p) {
                const int row = wv * 8 + p;
                load_lds16(src + (size_t)row * 512 + lane * 8, Kl[prv] + row * 520);
            }
        }

        // QK(kb): 4 independent 8-deep chains
        f32x4 s0a = {}, s0b = {}, s1a = {}, s1b = {};
#pragma unroll
        for (int ks = 0; ks < 16; ks += 2) {
            const bf16x8 b0 = *(const bf16x8*)(Kl[cur] + l15 * 520 + ks * 32 + quad * 8);
            const bf16x8 b1 = *(const bf16x8*)(Kl[cur] + (16 + l15) * 520 + ks * 32 + quad * 8);
            const bf16x8 c0 = *(const bf16x8*)(Kl[cur] + l15 * 520 + (ks + 1) * 32 + quad * 8);
            const bf16x8 c1 = *(const bf16x8*)(Kl[cur] + (16 + l15) * 520 + (ks + 1) * 32 + quad * 8);
            s0a = mfma16(aq[ks], b0, s0a);
            s1a = mfma16(aq[ks], b1, s1a);
            s0b = mfma16(aq[ks + 1], c0, s0b);
            s1b = mfma16(aq[ks + 1], c1, s1b);
        }

        // PV(kb-1): 32 independent MFMAs — fills QK dep-stalls + exp tail
        {
            bf16x8 ap[4];
#pragma unroll
            for (int qt = 0; qt < 4; ++qt)
                ap[qt] = *(const bf16x8*)(Pl[prv] + (qt * 16 + l15) * 40 + quad * 8);
#pragma unroll
            for (int dt = 0; dt < 8; ++dt)
#pragma unroll
                for (int qt = 0; qt < 4; ++qt)
                    acc[qt][dt] = mfma16(ap[qt], vb[dt], acc[qt][dt]);
        }

        // exp(kb) -> Pl[cur]
        const f32x4 sA = s0a + s0b, sB = s1a + s1b;
#pragma unroll
        for (int r = 0; r < 4; ++r) {
            const float p0 = exp2f(sA[r] * sc2);
            const float p1 = exp2f(sB[r] * sc2);
            lacc[r] += p0 + p1;
            Pl[cur][(wv * 16 + quad * 4 + r) * 40 + l15] = (bf16_t)p0;
            Pl[cur][(wv * 16 + quad * 4 + r) * 40 + 16 + l15] = (bf16_t)p1;
        }

        __syncthreads();
    }

    // ---- epilogue: PV(63) from Pl[1]
    {
        bf16x8 vb[8];
#pragma unroll
        for (int i = 0; i < 8; ++i)
            vb[i] = *(const bf16x8*)(Vbase + (size_t)(i * 16 + l15) * S_ +
                                     63 * 32 + quad * 8);
        bf16x8 ap[4];
#pragma unroll
        for (int qt = 0; qt < 4; ++qt)
            ap[qt] = *(const bf16x8*)(Pl[1] + (qt * 16 + l15) * 40 + quad * 8);
#pragma unroll
        for (int dt = 0; dt < 8; ++dt)
#pragma unroll
            for (int qt = 0; qt < 4; ++qt)
                acc[qt][dt] = mfma16(ap[qt], vb[dt], acc[qt][dt]);
    }

    // one-time row-sum reduction (16 lanes per quad) and publish
    {
        float lrow[4];
#pragma unroll
        for (int r = 0; r < 4; ++r) {
            float v = lacc[r];
#pragma unroll
            for (int off = 1; off < 16; off <<= 1) v += __shfl_xor(v, off, 64);
            lrow[r] = v;
        }
        if (l15 == 0) {
#pragma unroll
            for (int r = 0; r < 4; ++r) lsumL[wv * 16 + quad * 4 + r] = lrow[r];
        }
    }
    __syncthreads();

#pragma unroll
    for (int qt = 0; qt < 4; ++qt) {
        f32x4 inv;
#pragma unroll
        for (int r = 0; r < 4; ++r) inv[r] = 1.0f / lsumL[qt * 16 + quad * 4 + r];
#pragma unroll
        for (int dt = 0; dt < 8; ++dt) {
            const int d = wv * 128 + dt * 16 + l15;
#pragma unroll
            for (int r = 0; r < 4; ++r) {
                const float v = acc[qt][dt][r] * inv[r];
                const size_t idx =
                    (size_t)(b * S_ + q0 + qt * 16 + quad * 4 + r) * 512 + d;
                if (mode == 0)      attn[(size_t)w * M_TOT * 512 + idx] = (bf16_t)v;
                else if (mode == 1) out[idx] = X[idx] + Y[idx] + v;
                else                out[idx] += v;
            }
        }
    }
}

// ---------------------------------------------------------------------------
// k4: out = X + Y + attn0 + attn1
// ---------------------------------------------------------------------------
__global__ __launch_bounds__(256) void k_add(
    const float* __restrict__ X, const float* __restrict__ Y,
    const bf16_t* __restrict__ a0, const bf16_t* __restrict__ a1,
    float* __restrict__ out)
{
    const size_t i = ((size_t)blockIdx.x * 256 + threadIdx.x) * 4;
    const float4 x = *(const float4*)(X + i);
    const float4 y = *(const float4*)(Y + i);
    const bf16x4 v0 = *(const bf16x4*)(a0 + i);
    const bf16x4 v1 = *(const bf16x4*)(a1 + i);
    float4 o;
    o.x = x.x + y.x + (float)v0[0] + (float)v1[0];
    o.y = x.y + y.y + (float)v0[1] + (float)v1[1];
    o.z = x.z + y.z + (float)v0[2] + (float)v1[2];
    o.w = x.w + y.w + (float)v0[3] + (float)v1[3];
    *(float4*)(out + i) = o;
}

extern "C" void kernel_launch(void* const* d_in, const int* in_sizes, int n_in,
                              void* d_out, int out_size, void* d_ws, size_t ws_size,
                              hipStream_t stream)
{
    const float* X   = (const float*)d_in[0];
    const float* Y   = (const float*)d_in[1];
    const float* Wxq = (const float*)d_in[2];
    const float* bxq = (const float*)d_in[3];
    const float* Wyq = (const float*)d_in[4];
    const float* byq = (const float*)d_in[5];
    const float* Wfk = (const float*)d_in[6];
    const float* bfk = (const float*)d_in[7];
    const float* Wfv = (const float*)d_in[8];
    const float* bfv = (const float*)d_in[9];
    float* out = (float*)d_out;
    char*  ws  = (char*)d_ws;

    // ws layout (bytes): Qcat 32MiB | Kf 16MiB | Vt 16MiB | attn 2x16MiB
    bf16_t* Qcat = (bf16_t*)(ws);
    bf16_t* Kf   = (bf16_t*)(ws + (size_t)33554432);
    bf16_t* Vt   = (bf16_t*)(ws + (size_t)50331648);
    bf16_t* attn = (bf16_t*)(ws + (size_t)67108864);
    const bool big = ws_size >= (size_t)100663296;

    k_qgemm<<<dim3(128, 8), 256, 0, stream>>>(X, Y, Wxq, bxq, Wyq, byq, Qcat);
    k_kvgemm<<<dim3(128, 8), 256, 0, stream>>>(Qcat, Wfk, bfk, Wfv, bfv, Kf, Vt);
    if (big) {
        k_attn<<<dim3(32, 8, 2), 256, 0, stream>>>(Qcat, Kf, Vt, X, Y, out, attn, 0, 0);
        k_add<<<dim3(8192), 256, 0, stream>>>(X, Y, attn, attn + (size_t)M_TOT * 512, out);
    } else {
        k_attn<<<dim3(32, 8, 1), 256, 0, stream>>>(Qcat, Kf, Vt, X, Y, out, attn, 1, 0);
        k_attn<<<dim3(32, 8, 1), 256, 0, stream>>>(Qcat, Kf, Vt, X, Y, out, attn, 2, 1);
    }
}

// Round 8
// 471.064 us; speedup vs baseline: 1.2781x; 1.0116x over previous
//
#include <hip/hip_runtime.h>

// ---------------------------------------------------------------------------
// CA2_82300163326041: dual cross-attention fusion, MI355X bf16-MFMA pipeline.
// R8 restructure: attn is latency-locked (241 µs, regs 256/wave = 2 w/SIMD,
// R2/R3/R6/R7 levers all neutral-or-worse) — this round attacks the OTHER
// ~235 µs: k1/k2 ran ~220 TF because operands were fp32 reg-staged with
// in-loop cvt (Common-mistake #1). Now:
//   k_cvt  : X,Y -> bf16 (Xb @ ws+80M; Yb aliases Kf region, dead at k2)
//   k_cvtw : 4 weights -> bf16 concat Wb @ ws+64M (3 MB; attn1 region,
//            dead before k3 writes attn1 there)
//   k_qgemm_bb : Qcat = [Xb|Yb] @ [Wxqb|Wyqb]^T + bias — BOTH operands
//            global_load_lds 16B DMA (m97 structure, ~874 TF class)
//   k_kvgemm_bb: Kf, Vt (transposed V) — both operands DMA
//   k_attn : unchanged 241 µs body; mode 3: w=0 writes out=X+Y+v directly
//            (kills attn0 buffer), w=1 writes attn1.
//   k_add2 : out += attn1
// ws layout: Qcat 0-32M | Kf 32-48M (Yb alias pre-k2) | Vt 48-64M |
//            Wb/attn1 64-80M | Xb 80-96M
// MFMA layouts (measured, guide §3): A[m=lane&15][k=quad*8+j],
// Bt[n=lane&15][k=quad*8+j], D: col=lane&15, row=quad*4+reg.
// ---------------------------------------------------------------------------

#define B_    8
#define S_    2048
#define D_    512
#define M_TOT (B_ * S_) /* 16384 */

typedef __bf16 bf16_t;
typedef __bf16 bf16x8 __attribute__((ext_vector_type(8)));
typedef __bf16 bf16x4 __attribute__((ext_vector_type(4)));
typedef float  f32x4  __attribute__((ext_vector_type(4)));

typedef __attribute__((address_space(1))) const void* gas_cv;
typedef __attribute__((address_space(3))) void*       las_v;

__device__ __forceinline__ f32x4 mfma16(bf16x8 a, bf16x8 b, f32x4 c) {
    return __builtin_amdgcn_mfma_f32_16x16x32_bf16(a, b, c, 0, 0, 0);
}
__device__ __forceinline__ void load_lds16(const void* g, void* l) {
    __builtin_amdgcn_global_load_lds((gas_cv)g, (las_v)l, 16, 0, 0);
}

// ---------------------------------------------------------------------------
// k_cvt: X,Y fp32 -> bf16
// ---------------------------------------------------------------------------
__global__ __launch_bounds__(256) void k_cvt(
    const float* __restrict__ X, const float* __restrict__ Y,
    bf16_t* __restrict__ Xb, bf16_t* __restrict__ Yb)
{
    const int n4 = M_TOT * 512 / 4;
    for (int i = blockIdx.x * 256 + threadIdx.x; i < n4; i += 2048 * 256) {
        const float4 x = *(const float4*)(X + (size_t)i * 4);
        bf16x4 px = { (bf16_t)x.x, (bf16_t)x.y, (bf16_t)x.z, (bf16_t)x.w };
        *(bf16x4*)(Xb + (size_t)i * 4) = px;
        const float4 y = *(const float4*)(Y + (size_t)i * 4);
        bf16x4 py = { (bf16_t)y.x, (bf16_t)y.y, (bf16_t)y.z, (bf16_t)y.w };
        *(bf16x4*)(Yb + (size_t)i * 4) = py;
    }
}

// ---------------------------------------------------------------------------
// k_cvtw: weights fp32 -> bf16 concat [Wxqb 256K | Wyqb 256K | Wfkb 512K |
// Wfvb 512K] elems. Grid 1536x256 = exactly 393216 float4s.
// ---------------------------------------------------------------------------
__global__ __launch_bounds__(256) void k_cvtw(
    const float* __restrict__ Wxq, const float* __restrict__ Wyq,
    const float* __restrict__ Wfk, const float* __restrict__ Wfv,
    bf16_t* __restrict__ Wb)
{
    const int j = blockIdx.x * 256 + threadIdx.x;   // float4 index
    const float* src; int sj;
    if (j < 65536)       { src = Wxq; sj = j; }
    else if (j < 131072) { src = Wyq; sj = j - 65536; }
    else if (j < 262144) { src = Wfk; sj = j - 131072; }
    else                 { src = Wfv; sj = j - 262144; }
    const float4 v = *(const float4*)(src + (size_t)sj * 4);
    bf16x4 p = { (bf16_t)v.x, (bf16_t)v.y, (bf16_t)v.z, (bf16_t)v.w };
    *(bf16x4*)(Wb + (size_t)j * 4) = p;
}

// ---------------------------------------------------------------------------
// k_qgemm_bb: Qcat = [Xb|Yb] @ [Wxqb|Wyqb]^T + bias. K=512. BOTH operands
// bf16 DMA into linear [128][32] LDS (m97 pattern).
// ---------------------------------------------------------------------------
__global__ __launch_bounds__(256) void k_qgemm_bb(
    const bf16_t* __restrict__ Xb, const bf16_t* __restrict__ Yb,
    const bf16_t* __restrict__ Wb,
    const float* __restrict__ bxq, const float* __restrict__ byq,
    bf16_t* __restrict__ Qcat)
{
    __shared__ __attribute__((aligned(16))) bf16_t Al[128 * 32];
    __shared__ __attribute__((aligned(16))) bf16_t Bl[128 * 32];
    const int m0 = blockIdx.x * 128;
    const int n0 = blockIdx.y * 128;           // N = 1024 (Q1 | Q2)
    const bool second = (n0 >= 512);
    const bf16_t* A   = second ? Yb : Xb;
    const bf16_t* W   = Wb + (second ? 262144 : 0);
    const float* bias = second ? byq : bxq;
    const int nw = n0 & 511;
    const int t    = threadIdx.x;
    const int lane = t & 63;
    const int wv   = t >> 6;
    const int wm   = (wv & 1) * 64;
    const int wn   = (wv >> 1) * 64;
    const int l15  = lane & 15;
    const int quad = lane >> 4;

    const int ar0 = t >> 2,          ac0 = (t & 3) * 8;
    const int ar1 = (256 + t) >> 2,  ac1 = ((256 + t) & 3) * 8;

    f32x4 acc[4][4] = {};

    for (int k0 = 0; k0 < 512; k0 += 32) {
        __syncthreads();
        load_lds16(A + (size_t)(m0 + ar0) * 512 + k0 + ac0, Al + t * 8);
        load_lds16(A + (size_t)(m0 + ar1) * 512 + k0 + ac1, Al + (256 + t) * 8);
        load_lds16(W + (size_t)(nw + ar0) * 512 + k0 + ac0, Bl + t * 8);
        load_lds16(W + (size_t)(nw + ar1) * 512 + k0 + ac1, Bl + (256 + t) * 8);
        __syncthreads();
        bf16x8 af[4], bfr[4];
#pragma unroll
        for (int i = 0; i < 4; ++i)
            af[i] = *(const bf16x8*)(Al + (wm + i * 16 + l15) * 32 + quad * 8);
#pragma unroll
        for (int i = 0; i < 4; ++i)
            bfr[i] = *(const bf16x8*)(Bl + (wn + i * 16 + l15) * 32 + quad * 8);
#pragma unroll
        for (int mt = 0; mt < 4; ++mt)
#pragma unroll
            for (int nt = 0; nt < 4; ++nt)
                acc[mt][nt] = mfma16(af[mt], bfr[nt], acc[mt][nt]);
    }

#pragma unroll
    for (int nt = 0; nt < 4; ++nt) {
        const int col  = n0 + wn + nt * 16 + l15;
        const float bv = bias[col & 511];
#pragma unroll
        for (int mt = 0; mt < 4; ++mt) {
            const int rowb = m0 + wm + mt * 16 + quad * 4;
#pragma unroll
            for (int r = 0; r < 4; ++r)
                Qcat[(size_t)(rowb + r) * 1024 + col] = (bf16_t)(acc[mt][nt][r] + bv);
        }
    }
}

// ---------------------------------------------------------------------------
// k_kvgemm_bb: [Kf | Vf] = Qcat @ [Wfkb | Wfvb]^T + bias. K=1024. Both
// operands bf16 DMA. Vf stored TRANSPOSED per batch Vt[b][d][s] via LDS.
// ---------------------------------------------------------------------------
__global__ __launch_bounds__(256) void k_kvgemm_bb(
    const bf16_t* __restrict__ Qcat,
    const bf16_t* __restrict__ Wfkb, const float* __restrict__ bfk,
    const bf16_t* __restrict__ Wfvb, const float* __restrict__ bfv,
    bf16_t* __restrict__ Kf, bf16_t* __restrict__ Vt)
{
    __shared__ __attribute__((aligned(16))) union {
        struct { bf16_t Al[128 * 32]; bf16_t Bl[128 * 32]; } g;
        bf16_t T[128 * 132];   // [d_local][s_local], pad 128->132
    } sm;
    const int m0 = blockIdx.x * 128;
    const int n0 = blockIdx.y * 128;           // N = 1024 (Kf | Vf)
    const bool isV = (n0 >= 512);
    const bf16_t* W   = isV ? Wfvb : Wfkb;
    const float* bias = isV ? bfv : bfk;
    const int nw = n0 & 511;
    const int t    = threadIdx.x;
    const int lane = t & 63;
    const int wv   = t >> 6;
    const int wm   = (wv & 1) * 64;
    const int wn   = (wv >> 1) * 64;
    const int l15  = lane & 15;
    const int quad = lane >> 4;

    const int ar0 = t >> 2,          ac0 = (t & 3) * 8;
    const int ar1 = (256 + t) >> 2,  ac1 = ((256 + t) & 3) * 8;

    f32x4 acc[4][4] = {};

    for (int k0 = 0; k0 < 1024; k0 += 32) {
        __syncthreads();
        load_lds16(Qcat + (size_t)(m0 + ar0) * 1024 + k0 + ac0, sm.g.Al + t * 8);
        load_lds16(Qcat + (size_t)(m0 + ar1) * 1024 + k0 + ac1, sm.g.Al + (256 + t) * 8);
        load_lds16(W + (size_t)(nw + ar0) * 1024 + k0 + ac0, sm.g.Bl + t * 8);
        load_lds16(W + (size_t)(nw + ar1) * 1024 + k0 + ac1, sm.g.Bl + (256 + t) * 8);
        __syncthreads();
        bf16x8 af[4], bfr[4];
#pragma unroll
        for (int i = 0; i < 4; ++i)
            af[i] = *(const bf16x8*)(sm.g.Al + (wm + i * 16 + l15) * 32 + quad * 8);
#pragma unroll
        for (int i = 0; i < 4; ++i)
            bfr[i] = *(const bf16x8*)(sm.g.Bl + (wn + i * 16 + l15) * 32 + quad * 8);
#pragma unroll
        for (int mt = 0; mt < 4; ++mt)
#pragma unroll
            for (int nt = 0; nt < 4; ++nt)
                acc[mt][nt] = mfma16(af[mt], bfr[nt], acc[mt][nt]);
    }

    if (!isV) {
#pragma unroll
        for (int nt = 0; nt < 4; ++nt) {
            const int col  = n0 + wn + nt * 16 + l15;   // < 512
            const float bv = bias[col];
#pragma unroll
            for (int mt = 0; mt < 4; ++mt) {
                const int rowb = m0 + wm + mt * 16 + quad * 4;
#pragma unroll
                for (int r = 0; r < 4; ++r)
                    Kf[(size_t)(rowb + r) * 512 + col] = (bf16_t)(acc[mt][nt][r] + bv);
            }
        }
    } else {
        __syncthreads();   // staging reads of the last k-block are done
#pragma unroll
        for (int nt = 0; nt < 4; ++nt) {
            const int dl = wn + nt * 16 + l15;
            const float bv = bias[nw + dl];
#pragma unroll
            for (int mt = 0; mt < 4; ++mt) {
                const int sl = wm + mt * 16 + quad * 4;
#pragma unroll
                for (int r = 0; r < 4; ++r)
                    sm.T[dl * 132 + sl + r] = (bf16_t)(acc[mt][nt][r] + bv);
            }
        }
        __syncthreads();
        const int bb = m0 >> 11;             // batch
        const int sb = m0 & 2047;
        const int half = lane >> 5;
        const int sl4  = (lane & 31) * 4;
#pragma unroll
        for (int i = 0; i < 16; ++i) {
            const int dl = wv * 32 + i * 2 + half;
            const bf16x4 v = *(const bf16x4*)(sm.T + dl * 132 + sl4);
            *(bf16x4*)(Vt + (size_t)(bb * 512 + nw + dl) * 2048 + sb + sl4) = v;
        }
    }
}

// ---------------------------------------------------------------------------
// legacy k1/k2 (fp32 reg-staged) for the small-ws fallback path
// ---------------------------------------------------------------------------
__global__ __launch_bounds__(256) void k_qgemm(
    const float* __restrict__ X, const float* __restrict__ Y,
    const float* __restrict__ Wxq, const float* __restrict__ bxq,
    const float* __restrict__ Wyq, const float* __restrict__ byq,
    bf16_t* __restrict__ Qcat)
{
    __shared__ __attribute__((aligned(16))) bf16_t Al[128 * 40];
    __shared__ __attribute__((aligned(16))) bf16_t Bl[128 * 40];
    const int m0 = blockIdx.x * 128;
    const int n0 = blockIdx.y * 128;
    const bool second = (n0 >= 512);
    const float* A    = second ? Y : X;
    const float* W    = second ? Wyq : Wxq;
    const float* bias = second ? byq : bxq;
    const int nw = n0 & 511;
    const int t    = threadIdx.x;
    const int lane = t & 63;
    const int wv   = t >> 6;
    const int wm   = (wv & 1) * 64;
    const int wn   = (wv >> 1) * 64;
    const int l15  = lane & 15;
    const int quad = lane >> 4;

    f32x4 acc[4][4] = {};

    for (int k0 = 0; k0 < 512; k0 += 32) {
        __syncthreads();
#pragma unroll
        for (int p = 0; p < 4; ++p) {
            const int lin = p * 256 + t;
            const int row = lin >> 3;
            const int ch  = (lin & 7) * 4;
            const float4 va = *(const float4*)(A + (size_t)(m0 + row) * 512 + k0 + ch);
            bf16x4 pa = { (bf16_t)va.x, (bf16_t)va.y, (bf16_t)va.z, (bf16_t)va.w };
            *(bf16x4*)(Al + row * 40 + ch) = pa;
            const float4 vb = *(const float4*)(W + (size_t)(nw + row) * 512 + k0 + ch);
            bf16x4 pb = { (bf16_t)vb.x, (bf16_t)vb.y, (bf16_t)vb.z, (bf16_t)vb.w };
            *(bf16x4*)(Bl + row * 40 + ch) = pb;
        }
        __syncthreads();
        bf16x8 af[4], bfr[4];
#pragma unroll
        for (int i = 0; i < 4; ++i)
            af[i] = *(const bf16x8*)(Al + (wm + i * 16 + l15) * 40 + quad * 8);
#pragma unroll
        for (int i = 0; i < 4; ++i)
            bfr[i] = *(const bf16x8*)(Bl + (wn + i * 16 + l15) * 40 + quad * 8);
#pragma unroll
        for (int mt = 0; mt < 4; ++mt)
#pragma unroll
            for (int nt = 0; nt < 4; ++nt)
                acc[mt][nt] = mfma16(af[mt], bfr[nt], acc[mt][nt]);
    }

#pragma unroll
    for (int nt = 0; nt < 4; ++nt) {
        const int col  = n0 + wn + nt * 16 + l15;
        const float bv = bias[col & 511];
#pragma unroll
        for (int mt = 0; mt < 4; ++mt) {
            const int rowb = m0 + wm + mt * 16 + quad * 4;
#pragma unroll
            for (int r = 0; r < 4; ++r)
                Qcat[(size_t)(rowb + r) * 1024 + col] = (bf16_t)(acc[mt][nt][r] + bv);
        }
    }
}

__global__ __launch_bounds__(256) void k_kvgemm(
    const bf16_t* __restrict__ Qcat,
    const float* __restrict__ Wfk, const float* __restrict__ bfk,
    const float* __restrict__ Wfv, const float* __restrict__ bfv,
    bf16_t* __restrict__ Kf, bf16_t* __restrict__ Vt)
{
    __shared__ __attribute__((aligned(16))) union {
        struct { bf16_t Al[128 * 32]; bf16_t Bl[128 * 32]; } g;
        bf16_t T[128 * 132];
    } sm;
    const int m0 = blockIdx.x * 128;
    const int n0 = blockIdx.y * 128;
    const bool isV = (n0 >= 512);
    const float* W    = isV ? Wfv : Wfk;
    const float* bias = isV ? bfv : bfk;
    const int nw = n0 & 511;
    const int t    = threadIdx.x;
    const int lane = t & 63;
    const int wv   = t >> 6;
    const int wm   = (wv & 1) * 64;
    const int wn   = (wv >> 1) * 64;
    const int l15  = lane & 15;
    const int quad = lane >> 4;

    const int ar0 = t >> 2,          ac0 = (t & 3) * 8;
    const int ar1 = (256 + t) >> 2,  ac1 = ((256 + t) & 3) * 8;

    f32x4 acc[4][4] = {};

    for (int k0 = 0; k0 < 1024; k0 += 32) {
        __syncthreads();
        load_lds16(Qcat + (size_t)(m0 + ar0) * 1024 + k0 + ac0, sm.g.Al + t * 8);
        load_lds16(Qcat + (size_t)(m0 + ar1) * 1024 + k0 + ac1, sm.g.Al + (256 + t) * 8);
#pragma unroll
        for (int p = 0; p < 4; ++p) {
            const int lin = p * 256 + t;
            const int row = lin >> 3;
            const int ch  = (lin & 7) * 4;
            const float4 vb = *(const float4*)(W + (size_t)(nw + row) * 1024 + k0 + ch);
            bf16x4 pb = { (bf16_t)vb.x, (bf16_t)vb.y, (bf16_t)vb.z, (bf16_t)vb.w };
            *(bf16x4*)(sm.g.Bl + row * 32 + ch) = pb;
        }
        __syncthreads();
        bf16x8 af[4], bfr[4];
#pragma unroll
        for (int i = 0; i < 4; ++i)
            af[i] = *(const bf16x8*)(sm.g.Al + (wm + i * 16 + l15) * 32 + quad * 8);
#pragma unroll
        for (int i = 0; i < 4; ++i)
            bfr[i] = *(const bf16x8*)(sm.g.Bl + (wn + i * 16 + l15) * 32 + quad * 8);
#pragma unroll
        for (int mt = 0; mt < 4; ++mt)
#pragma unroll
            for (int nt = 0; nt < 4; ++nt)
                acc[mt][nt] = mfma16(af[mt], bfr[nt], acc[mt][nt]);
    }

    if (!isV) {
#pragma unroll
        for (int nt = 0; nt < 4; ++nt) {
            const int col  = n0 + wn + nt * 16 + l15;
            const float bv = bias[col];
#pragma unroll
            for (int mt = 0; mt < 4; ++mt) {
                const int rowb = m0 + wm + mt * 16 + quad * 4;
#pragma unroll
                for (int r = 0; r < 4; ++r)
                    Kf[(size_t)(rowb + r) * 512 + col] = (bf16_t)(acc[mt][nt][r] + bv);
            }
        }
    } else {
        __syncthreads();
#pragma unroll
        for (int nt = 0; nt < 4; ++nt) {
            const int dl = wn + nt * 16 + l15;
            const float bv = bias[nw + dl];
#pragma unroll
            for (int mt = 0; mt < 4; ++mt) {
                const int sl = wm + mt * 16 + quad * 4;
#pragma unroll
                for (int r = 0; r < 4; ++r)
                    sm.T[dl * 132 + sl + r] = (bf16_t)(acc[mt][nt][r] + bv);
            }
        }
        __syncthreads();
        const int bb = m0 >> 11;
        const int sb = m0 & 2047;
        const int half = lane >> 5;
        const int sl4  = (lane & 31) * 4;
#pragma unroll
        for (int i = 0; i < 16; ++i) {
            const int dl = wv * 32 + i * 2 + half;
            const bf16x4 v = *(const bf16x4*)(sm.T + dl * 132 + sl4);
            *(bf16x4*)(Vt + (size_t)(bb * 512 + nw + dl) * 2048 + sb + sl4) = v;
        }
    }
}

// ---------------------------------------------------------------------------
// k3: attention (R7 verified body, 241 µs). mode 3 added: w=0 -> out=X+Y+v
// (kills the attn0 buffer), w=1 -> attn[idx]=v (attn = attn1 base).
// ---------------------------------------------------------------------------
__global__ __launch_bounds__(256, 2) void k_attn(
    const bf16_t* __restrict__ Qcat, const bf16_t* __restrict__ Kf,
    const bf16_t* __restrict__ Vt,
    const float* __restrict__ X, const float* __restrict__ Y,
    float* __restrict__ out, bf16_t* __restrict__ attn,
    const int mode, const int which)
{
    __shared__ __attribute__((aligned(16))) bf16_t Kl[2][32 * 520];
    __shared__ __attribute__((aligned(16))) bf16_t Pl[2][64 * 40];
    __shared__ float lsumL[64];

    const int b = blockIdx.y;
    const int w = (mode == 1 || mode == 2) ? which : (int)blockIdx.z;
    const int t    = threadIdx.x;
    const int lane = t & 63;
    const int wv   = t >> 6;
    const int l15  = lane & 15;
    const int quad = lane >> 4;
    const int q0   = blockIdx.x * 64;
    const int qw   = q0 + wv * 16;

    const bf16_t* Kbase = Kf + (size_t)b * S_ * 512;
    const bf16_t* Vbase = Vt + ((size_t)b * 512 + wv * 128) * S_;

    bf16x8 aq[16];
    {
        const bf16_t* qp = Qcat + (size_t)(b * S_ + qw + l15) * 1024 + w * 512 + quad * 8;
#pragma unroll
        for (int ks = 0; ks < 16; ++ks) aq[ks] = *(const bf16x8*)(qp + ks * 32);
    }

    f32x4 acc[4][8] = {};
    float lacc[4] = { 0.f, 0.f, 0.f, 0.f };
    const float sc2 = 0.04419417382415922f * 1.4426950408889634f;

    // ---- prologue: K0 -> Kl[0]
#pragma unroll
    for (int p = 0; p < 8; ++p) {
        const int row = wv * 8 + p;
        load_lds16(Kbase + (size_t)row * 512 + lane * 8, Kl[0] + row * 520);
    }
    __syncthreads();

    // ---- peeled iter 0
    {
#pragma unroll
        for (int p = 0; p < 8; ++p) {
            const int row = wv * 8 + p;
            load_lds16(Kbase + (size_t)(32 + row) * 512 + lane * 8, Kl[1] + row * 520);
        }
        f32x4 s0a = {}, s0b = {}, s1a = {}, s1b = {};
#pragma unroll
        for (int ks = 0; ks < 16; ks += 2) {
            const bf16x8 b0 = *(const bf16x8*)(Kl[0] + l15 * 520 + ks * 32 + quad * 8);
            const bf16x8 b1 = *(const bf16x8*)(Kl[0] + (16 + l15) * 520 + ks * 32 + quad * 8);
            const bf16x8 c0 = *(const bf16x8*)(Kl[0] + l15 * 520 + (ks + 1) * 32 + quad * 8);
            const bf16x8 c1 = *(const bf16x8*)(Kl[0] + (16 + l15) * 520 + (ks + 1) * 32 + quad * 8);
            s0a = mfma16(aq[ks], b0, s0a);
            s1a = mfma16(aq[ks], b1, s1a);
            s0b = mfma16(aq[ks + 1], c0, s0b);
            s1b = mfma16(aq[ks + 1], c1, s1b);
        }
        const f32x4 sA = s0a + s0b, sB = s1a + s1b;
#pragma unroll
        for (int r = 0; r < 4; ++r) {
            const float p0 = exp2f(sA[r] * sc2);
            const float p1 = exp2f(sB[r] * sc2);
            lacc[r] += p0 + p1;
            Pl[0][(wv * 16 + quad * 4 + r) * 40 + l15] = (bf16_t)p0;
            Pl[0][(wv * 16 + quad * 4 + r) * 40 + 16 + l15] = (bf16_t)p1;
        }
        __syncthreads();
    }

    // ---- main loop kb = 1..63
    for (int kb = 1; kb < 64; ++kb) {
        const int cur = kb & 1;
        const int prv = cur ^ 1;

        bf16x8 vb[8];
#pragma unroll
        for (int i = 0; i < 8; ++i)
            vb[i] = *(const bf16x8*)(Vbase + (size_t)(i * 16 + l15) * S_ +
                                     (kb - 1) * 32 + quad * 8);

        {
            const bf16_t* src = Kbase + (size_t)(kb + 1) * 32 * 512;
#pragma unroll
            for (int p = 0; p < 8; ++p) {
                const int row = wv * 8 + p;
                load_lds16(src + (size_t)row * 512 + lane * 8, Kl[prv] + row * 520);
            }
        }

        f32x4 s0a = {}, s0b = {}, s1a = {}, s1b = {};
#pragma unroll
        for (int ks = 0; ks < 16; ks += 2) {
            const bf16x8 b0 = *(const bf16x8*)(Kl[cur] + l15 * 520 + ks * 32 + quad * 8);
            const bf16x8 b1 = *(const bf16x8*)(Kl[cur] + (16 + l15) * 520 + ks * 32 + quad * 8);
            const bf16x8 c0 = *(const bf16x8*)(Kl[cur] + l15 * 520 + (ks + 1) * 32 + quad * 8);
            const bf16x8 c1 = *(const bf16x8*)(Kl[cur] + (16 + l15) * 520 + (ks + 1) * 32 + quad * 8);
            s0a = mfma16(aq[ks], b0, s0a);
            s1a = mfma16(aq[ks], b1, s1a);
            s0b = mfma16(aq[ks + 1], c0, s0b);
            s1b = mfma16(aq[ks + 1], c1, s1b);
        }

        {
            bf16x8 ap[4];
#pragma unroll
            for (int qt = 0; qt < 4; ++qt)
                ap[qt] = *(const bf16x8*)(Pl[prv] + (qt * 16 + l15) * 40 + quad * 8);
#pragma unroll
            for (int dt = 0; dt < 8; ++dt)
#pragma unroll
                for (int qt = 0; qt < 4; ++qt)
                    acc[qt][dt] = mfma16(ap[qt], vb[dt], acc[qt][dt]);
        }

        const f32x4 sA = s0a + s0b, sB = s1a + s1b;
#pragma unroll
        for (int r = 0; r < 4; ++r) {
            const float p0 = exp2f(sA[r] * sc2);
            const float p1 = exp2f(sB[r] * sc2);
            lacc[r] += p0 + p1;
            Pl[cur][(wv * 16 + quad * 4 + r) * 40 + l15] = (bf16_t)p0;
            Pl[cur][(wv * 16 + quad * 4 + r) * 40 + 16 + l15] = (bf16_t)p1;
        }

        __syncthreads();
    }

    // ---- epilogue: PV(63) from Pl[1]
    {
        bf16x8 vb[8];
#pragma unroll
        for (int i = 0; i < 8; ++i)
            vb[i] = *(const bf16x8*)(Vbase + (size_t)(i * 16 + l15) * S_ +
                                     63 * 32 + quad * 8);
        bf16x8 ap[4];
#pragma unroll
        for (int qt = 0; qt < 4; ++qt)
            ap[qt] = *(const bf16x8*)(Pl[1] + (qt * 16 + l15) * 40 + quad * 8);
#pragma unroll
        for (int dt = 0; dt < 8; ++dt)
#pragma unroll
            for (int qt = 0; qt < 4; ++qt)
                acc[qt][dt] = mfma16(ap[qt], vb[dt], acc[qt][dt]);
    }

    {
        float lrow[4];
#pragma unroll
        for (int r = 0; r < 4; ++r) {
            float v = lacc[r];
#pragma unroll
            for (int off = 1; off < 16; off <<= 1) v += __shfl_xor(v, off, 64);
            lrow[r] = v;
        }
        if (l15 == 0) {
#pragma unroll
            for (int r = 0; r < 4; ++r) lsumL[wv * 16 + quad * 4 + r] = lrow[r];
        }
    }
    __syncthreads();

#pragma unroll
    for (int qt = 0; qt < 4; ++qt) {
        f32x4 inv;
#pragma unroll
        for (int r = 0; r < 4; ++r) inv[r] = 1.0f / lsumL[qt * 16 + quad * 4 + r];
#pragma unroll
        for (int dt = 0; dt < 8; ++dt) {
            const int d = wv * 128 + dt * 16 + l15;
#pragma unroll
            for (int r = 0; r < 4; ++r) {
                const float v = acc[qt][dt][r] * inv[r];
                const size_t idx =
                    (size_t)(b * S_ + q0 + qt * 16 + quad * 4 + r) * 512 + d;
                if (mode == 3) {
                    if (w == 0) out[idx] = X[idx] + Y[idx] + v;
                    else        attn[idx] = (bf16_t)v;
                } else if (mode == 0) {
                    attn[(size_t)w * M_TOT * 512 + idx] = (bf16_t)v;
                } else if (mode == 1) {
                    out[idx] = X[idx] + Y[idx] + v;
                } else {
                    out[idx] += v;
                }
            }
        }
    }
}

// ---------------------------------------------------------------------------
// k_add2: out += attn1
// ---------------------------------------------------------------------------
__global__ __launch_bounds__(256) void k_add2(
    const bf16_t* __restrict__ a1, float* __restrict__ out)
{
    const size_t i = ((size_t)blockIdx.x * 256 + threadIdx.x) * 4;
    float4 o = *(const float4*)(out + i);
    const bf16x4 v1 = *(const bf16x4*)(a1 + i);
    o.x += (float)v1[0];
    o.y += (float)v1[1];
    o.z += (float)v1[2];
    o.w += (float)v1[3];
    *(float4*)(out + i) = o;
}

extern "C" void kernel_launch(void* const* d_in, const int* in_sizes, int n_in,
                              void* d_out, int out_size, void* d_ws, size_t ws_size,
                              hipStream_t stream)
{
    const float* X   = (const float*)d_in[0];
    const float* Y   = (const float*)d_in[1];
    const float* Wxq = (const float*)d_in[2];
    const float* bxq = (const float*)d_in[3];
    const float* Wyq = (const float*)d_in[4];
    const float* byq = (const float*)d_in[5];
    const float* Wfk = (const float*)d_in[6];
    const float* bfk = (const float*)d_in[7];
    const float* Wfv = (const float*)d_in[8];
    const float* bfv = (const float*)d_in[9];
    float* out = (float*)d_out;
    char*  ws  = (char*)d_ws;

    // ws: Qcat 0-32M | Kf 32-48M | Vt 48-64M | Wb+attn1 64-80M | Xb 80-96M
    bf16_t* Qcat = (bf16_t*)(ws);
    bf16_t* Kf   = (bf16_t*)(ws + (size_t)33554432);
    bf16_t* Vt   = (bf16_t*)(ws + (size_t)50331648);
    bf16_t* Wb   = (bf16_t*)(ws + (size_t)67108864);  // 3 MB, dead before k3
    bf16_t* at1  = (bf16_t*)(ws + (size_t)67108864);  // attn1, written at k3
    bf16_t* Xb   = (bf16_t*)(ws + (size_t)83886080);
    bf16_t* Yb   = Kf;                                // alias: dead before k2 writes Kf
    const bool big = ws_size >= (size_t)100663296;

    if (big) {
        k_cvt<<<dim3(2048), 256, 0, stream>>>(X, Y, Xb, Yb);
        k_cvtw<<<dim3(1536), 256, 0, stream>>>(Wxq, Wyq, Wfk, Wfv, Wb);
        k_qgemm_bb<<<dim3(128, 8), 256, 0, stream>>>(Xb, Yb, Wb, bxq, byq, Qcat);
        k_kvgemm_bb<<<dim3(128, 8), 256, 0, stream>>>(Qcat, Wb + 524288, bfk,
                                                      Wb + 1048576, bfv, Kf, Vt);
        k_attn<<<dim3(32, 8, 2), 256, 0, stream>>>(Qcat, Kf, Vt, X, Y, out, at1, 3, 0);
        k_add2<<<dim3(8192), 256, 0, stream>>>(at1, out);
    } else {
        k_qgemm<<<dim3(128, 8), 256, 0, stream>>>(X, Y, Wxq, bxq, Wyq, byq, Qcat);
        k_kvgemm<<<dim3(128, 8), 256, 0, stream>>>(Qcat, Wfk, bfk, Wfv, bfv, Kf, Vt);
        k_attn<<<dim3(32, 8, 1), 256, 0, stream>>>(Qcat, Kf, Vt, X, Y, out, at1, 1, 0);
        k_attn<<<dim3(32, 8, 1), 256, 0, stream>>>(Qcat, Kf, Vt, X, Y, out, at1, 2, 1);
    }
}

// Round 9
// 441.987 us; speedup vs baseline: 1.3621x; 1.0658x over previous
//
#include <hip/hip_runtime.h>

// ---------------------------------------------------------------------------
// CA2_82300163326041: dual cross-attention fusion, MI355X bf16-MFMA pipeline.
// R9 consolidation: keep R8's bb-GEMM pipeline (both operands DMA-staged
// bf16; saved ~39 µs), REVERT R8's mode-3 epilogue fusion (it inlined k4's
// 96 MB of fp32 traffic into the latency-locked attn epilogue: +34 µs).
// attn is back to the proven mode-0 (write bf16 attn0/attn1) + k_add.
//   k_cvt  : X,Y -> bf16 (Xb @ ws+80M; Yb aliases Kf region, dead at k2)
//   k_cvtw : 4 weights -> bf16 concat Wb @ ws+64M
//   k_qgemm_bb : Qcat = [Xb|Yb]@[Wxqb|Wyqb]^T + bias, both operands DMA
//   k_kvgemm_bb: Kf, Vt (transposed V), both operands DMA
//   k_attn : proven 241 µs body, mode 0 -> attn0/attn1 (bf16)
//   k_add  : out = X + Y + attn0 + attn1
// ws: Qcat 0-32M | Kf 32-48M (Yb alias pre-k2) | Vt 48-64M |
//     Wb 64-67M / attn0 64-80M (Wb dead after k2) | Xb / attn1 80-96M
//     (Xb dead after k1)
// Ledger: R2 setprio/R3 lockstep-swizzle/R6 stagger/R7 V-first/R8 fusion
// all neutral-or-worse on attn — attn floor 241 µs at 2 waves/SIMD
// (acc 128 AGPR + 128 VGPR = full RF). GEMM side is the open front.
// ---------------------------------------------------------------------------

#define B_    8
#define S_    2048
#define D_    512
#define M_TOT (B_ * S_) /* 16384 */

typedef __bf16 bf16_t;
typedef __bf16 bf16x8 __attribute__((ext_vector_type(8)));
typedef __bf16 bf16x4 __attribute__((ext_vector_type(4)));
typedef float  f32x4  __attribute__((ext_vector_type(4)));

typedef __attribute__((address_space(1))) const void* gas_cv;
typedef __attribute__((address_space(3))) void*       las_v;

__device__ __forceinline__ f32x4 mfma16(bf16x8 a, bf16x8 b, f32x4 c) {
    return __builtin_amdgcn_mfma_f32_16x16x32_bf16(a, b, c, 0, 0, 0);
}
__device__ __forceinline__ void load_lds16(const void* g, void* l) {
    __builtin_amdgcn_global_load_lds((gas_cv)g, (las_v)l, 16, 0, 0);
}

// ---------------------------------------------------------------------------
// k_cvt: X,Y fp32 -> bf16
// ---------------------------------------------------------------------------
__global__ __launch_bounds__(256) void k_cvt(
    const float* __restrict__ X, const float* __restrict__ Y,
    bf16_t* __restrict__ Xb, bf16_t* __restrict__ Yb)
{
    const int n4 = M_TOT * 512 / 4;
    for (int i = blockIdx.x * 256 + threadIdx.x; i < n4; i += 2048 * 256) {
        const float4 x = *(const float4*)(X + (size_t)i * 4);
        bf16x4 px = { (bf16_t)x.x, (bf16_t)x.y, (bf16_t)x.z, (bf16_t)x.w };
        *(bf16x4*)(Xb + (size_t)i * 4) = px;
        const float4 y = *(const float4*)(Y + (size_t)i * 4);
        bf16x4 py = { (bf16_t)y.x, (bf16_t)y.y, (bf16_t)y.z, (bf16_t)y.w };
        *(bf16x4*)(Yb + (size_t)i * 4) = py;
    }
}

// ---------------------------------------------------------------------------
// k_cvtw: weights fp32 -> bf16 concat [Wxqb 256K | Wyqb 256K | Wfkb 512K |
// Wfvb 512K] elems. Grid 1536x256 = exactly 393216 float4s.
// ---------------------------------------------------------------------------
__global__ __launch_bounds__(256) void k_cvtw(
    const float* __restrict__ Wxq, const float* __restrict__ Wyq,
    const float* __restrict__ Wfk, const float* __restrict__ Wfv,
    bf16_t* __restrict__ Wb)
{
    const int j = blockIdx.x * 256 + threadIdx.x;   // float4 index
    const float* src; int sj;
    if (j < 65536)       { src = Wxq; sj = j; }
    else if (j < 131072) { src = Wyq; sj = j - 65536; }
    else if (j < 262144) { src = Wfk; sj = j - 131072; }
    else                 { src = Wfv; sj = j - 262144; }
    const float4 v = *(const float4*)(src + (size_t)sj * 4);
    bf16x4 p = { (bf16_t)v.x, (bf16_t)v.y, (bf16_t)v.z, (bf16_t)v.w };
    *(bf16x4*)(Wb + (size_t)j * 4) = p;
}

// ---------------------------------------------------------------------------
// k_qgemm_bb: Qcat = [Xb|Yb] @ [Wxqb|Wyqb]^T + bias. K=512. BOTH operands
// bf16 DMA into linear [128][32] LDS (m97 pattern).
// ---------------------------------------------------------------------------
__global__ __launch_bounds__(256) void k_qgemm_bb(
    const bf16_t* __restrict__ Xb, const bf16_t* __restrict__ Yb,
    const bf16_t* __restrict__ Wb,
    const float* __restrict__ bxq, const float* __restrict__ byq,
    bf16_t* __restrict__ Qcat)
{
    __shared__ __attribute__((aligned(16))) bf16_t Al[128 * 32];
    __shared__ __attribute__((aligned(16))) bf16_t Bl[128 * 32];
    const int m0 = blockIdx.x * 128;
    const int n0 = blockIdx.y * 128;           // N = 1024 (Q1 | Q2)
    const bool second = (n0 >= 512);
    const bf16_t* A   = second ? Yb : Xb;
    const bf16_t* W   = Wb + (second ? 262144 : 0);
    const float* bias = second ? byq : bxq;
    const int nw = n0 & 511;
    const int t    = threadIdx.x;
    const int lane = t & 63;
    const int wv   = t >> 6;
    const int wm   = (wv & 1) * 64;
    const int wn   = (wv >> 1) * 64;
    const int l15  = lane & 15;
    const int quad = lane >> 4;

    const int ar0 = t >> 2,          ac0 = (t & 3) * 8;
    const int ar1 = (256 + t) >> 2,  ac1 = ((256 + t) & 3) * 8;

    f32x4 acc[4][4] = {};

    for (int k0 = 0; k0 < 512; k0 += 32) {
        __syncthreads();
        load_lds16(A + (size_t)(m0 + ar0) * 512 + k0 + ac0, Al + t * 8);
        load_lds16(A + (size_t)(m0 + ar1) * 512 + k0 + ac1, Al + (256 + t) * 8);
        load_lds16(W + (size_t)(nw + ar0) * 512 + k0 + ac0, Bl + t * 8);
        load_lds16(W + (size_t)(nw + ar1) * 512 + k0 + ac1, Bl + (256 + t) * 8);
        __syncthreads();
        bf16x8 af[4], bfr[4];
#pragma unroll
        for (int i = 0; i < 4; ++i)
            af[i] = *(const bf16x8*)(Al + (wm + i * 16 + l15) * 32 + quad * 8);
#pragma unroll
        for (int i = 0; i < 4; ++i)
            bfr[i] = *(const bf16x8*)(Bl + (wn + i * 16 + l15) * 32 + quad * 8);
#pragma unroll
        for (int mt = 0; mt < 4; ++mt)
#pragma unroll
            for (int nt = 0; nt < 4; ++nt)
                acc[mt][nt] = mfma16(af[mt], bfr[nt], acc[mt][nt]);
    }

#pragma unroll
    for (int nt = 0; nt < 4; ++nt) {
        const int col  = n0 + wn + nt * 16 + l15;
        const float bv = bias[col & 511];
#pragma unroll
        for (int mt = 0; mt < 4; ++mt) {
            const int rowb = m0 + wm + mt * 16 + quad * 4;
#pragma unroll
            for (int r = 0; r < 4; ++r)
                Qcat[(size_t)(rowb + r) * 1024 + col] = (bf16_t)(acc[mt][nt][r] + bv);
        }
    }
}

// ---------------------------------------------------------------------------
// k_kvgemm_bb: [Kf | Vf] = Qcat @ [Wfkb | Wfvb]^T + bias. K=1024. Both
// operands bf16 DMA. Vf stored TRANSPOSED per batch Vt[b][d][s] via LDS.
// ---------------------------------------------------------------------------
__global__ __launch_bounds__(256) void k_kvgemm_bb(
    const bf16_t* __restrict__ Qcat,
    const bf16_t* __restrict__ Wfkb, const float* __restrict__ bfk,
    const bf16_t* __restrict__ Wfvb, const float* __restrict__ bfv,
    bf16_t* __restrict__ Kf, bf16_t* __restrict__ Vt)
{
    __shared__ __attribute__((aligned(16))) union {
        struct { bf16_t Al[128 * 32]; bf16_t Bl[128 * 32]; } g;
        bf16_t T[128 * 132];   // [d_local][s_local], pad 128->132
    } sm;
    const int m0 = blockIdx.x * 128;
    const int n0 = blockIdx.y * 128;           // N = 1024 (Kf | Vf)
    const bool isV = (n0 >= 512);
    const bf16_t* W   = isV ? Wfvb : Wfkb;
    const float* bias = isV ? bfv : bfk;
    const int nw = n0 & 511;
    const int t    = threadIdx.x;
    const int lane = t & 63;
    const int wv   = t >> 6;
    const int wm   = (wv & 1) * 64;
    const int wn   = (wv >> 1) * 64;
    const int l15  = lane & 15;
    const int quad = lane >> 4;

    const int ar0 = t >> 2,          ac0 = (t & 3) * 8;
    const int ar1 = (256 + t) >> 2,  ac1 = ((256 + t) & 3) * 8;

    f32x4 acc[4][4] = {};

    for (int k0 = 0; k0 < 1024; k0 += 32) {
        __syncthreads();
        load_lds16(Qcat + (size_t)(m0 + ar0) * 1024 + k0 + ac0, sm.g.Al + t * 8);
        load_lds16(Qcat + (size_t)(m0 + ar1) * 1024 + k0 + ac1, sm.g.Al + (256 + t) * 8);
        load_lds16(W + (size_t)(nw + ar0) * 1024 + k0 + ac0, sm.g.Bl + t * 8);
        load_lds16(W + (size_t)(nw + ar1) * 1024 + k0 + ac1, sm.g.Bl + (256 + t) * 8);
        __syncthreads();
        bf16x8 af[4], bfr[4];
#pragma unroll
        for (int i = 0; i < 4; ++i)
            af[i] = *(const bf16x8*)(sm.g.Al + (wm + i * 16 + l15) * 32 + quad * 8);
#pragma unroll
        for (int i = 0; i < 4; ++i)
            bfr[i] = *(const bf16x8*)(sm.g.Bl + (wn + i * 16 + l15) * 32 + quad * 8);
#pragma unroll
        for (int mt = 0; mt < 4; ++mt)
#pragma unroll
            for (int nt = 0; nt < 4; ++nt)
                acc[mt][nt] = mfma16(af[mt], bfr[nt], acc[mt][nt]);
    }

    if (!isV) {
#pragma unroll
        for (int nt = 0; nt < 4; ++nt) {
            const int col  = n0 + wn + nt * 16 + l15;   // < 512
            const float bv = bias[col];
#pragma unroll
            for (int mt = 0; mt < 4; ++mt) {
                const int rowb = m0 + wm + mt * 16 + quad * 4;
#pragma unroll
                for (int r = 0; r < 4; ++r)
                    Kf[(size_t)(rowb + r) * 512 + col] = (bf16_t)(acc[mt][nt][r] + bv);
            }
        }
    } else {
        __syncthreads();   // staging reads of the last k-block are done
#pragma unroll
        for (int nt = 0; nt < 4; ++nt) {
            const int dl = wn + nt * 16 + l15;
            const float bv = bias[nw + dl];
#pragma unroll
            for (int mt = 0; mt < 4; ++mt) {
                const int sl = wm + mt * 16 + quad * 4;
#pragma unroll
                for (int r = 0; r < 4; ++r)
                    sm.T[dl * 132 + sl + r] = (bf16_t)(acc[mt][nt][r] + bv);
            }
        }
        __syncthreads();
        const int bb = m0 >> 11;             // batch
        const int sb = m0 & 2047;
        const int half = lane >> 5;
        const int sl4  = (lane & 31) * 4;
#pragma unroll
        for (int i = 0; i < 16; ++i) {
            const int dl = wv * 32 + i * 2 + half;
            const bf16x4 v = *(const bf16x4*)(sm.T + dl * 132 + sl4);
            *(bf16x4*)(Vt + (size_t)(bb * 512 + nw + dl) * 2048 + sb + sl4) = v;
        }
    }
}

// ---------------------------------------------------------------------------
// legacy k1/k2 (fp32 reg-staged) for the small-ws fallback path
// ---------------------------------------------------------------------------
__global__ __launch_bounds__(256) void k_qgemm(
    const float* __restrict__ X, const float* __restrict__ Y,
    const float* __restrict__ Wxq, const float* __restrict__ bxq,
    const float* __restrict__ Wyq, const float* __restrict__ byq,
    bf16_t* __restrict__ Qcat)
{
    __shared__ __attribute__((aligned(16))) bf16_t Al[128 * 40];
    __shared__ __attribute__((aligned(16))) bf16_t Bl[128 * 40];
    const int m0 = blockIdx.x * 128;
    const int n0 = blockIdx.y * 128;
    const bool second = (n0 >= 512);
    const float* A    = second ? Y : X;
    const float* W    = second ? Wyq : Wxq;
    const float* bias = second ? byq : bxq;
    const int nw = n0 & 511;
    const int t    = threadIdx.x;
    const int lane = t & 63;
    const int wv   = t >> 6;
    const int wm   = (wv & 1) * 64;
    const int wn   = (wv >> 1) * 64;
    const int l15  = lane & 15;
    const int quad = lane >> 4;

    f32x4 acc[4][4] = {};

    for (int k0 = 0; k0 < 512; k0 += 32) {
        __syncthreads();
#pragma unroll
        for (int p = 0; p < 4; ++p) {
            const int lin = p * 256 + t;
            const int row = lin >> 3;
            const int ch  = (lin & 7) * 4;
            const float4 va = *(const float4*)(A + (size_t)(m0 + row) * 512 + k0 + ch);
            bf16x4 pa = { (bf16_t)va.x, (bf16_t)va.y, (bf16_t)va.z, (bf16_t)va.w };
            *(bf16x4*)(Al + row * 40 + ch) = pa;
            const float4 vb = *(const float4*)(W + (size_t)(nw + row) * 512 + k0 + ch);
            bf16x4 pb = { (bf16_t)vb.x, (bf16_t)vb.y, (bf16_t)vb.z, (bf16_t)vb.w };
            *(bf16x4*)(Bl + row * 40 + ch) = pb;
        }
        __syncthreads();
        bf16x8 af[4], bfr[4];
#pragma unroll
        for (int i = 0; i < 4; ++i)
            af[i] = *(const bf16x8*)(Al + (wm + i * 16 + l15) * 40 + quad * 8);
#pragma unroll
        for (int i = 0; i < 4; ++i)
            bfr[i] = *(const bf16x8*)(Bl + (wn + i * 16 + l15) * 40 + quad * 8);
#pragma unroll
        for (int mt = 0; mt < 4; ++mt)
#pragma unroll
            for (int nt = 0; nt < 4; ++nt)
                acc[mt][nt] = mfma16(af[mt], bfr[nt], acc[mt][nt]);
    }

#pragma unroll
    for (int nt = 0; nt < 4; ++nt) {
        const int col  = n0 + wn + nt * 16 + l15;
        const float bv = bias[col & 511];
#pragma unroll
        for (int mt = 0; mt < 4; ++mt) {
            const int rowb = m0 + wm + mt * 16 + quad * 4;
#pragma unroll
            for (int r = 0; r < 4; ++r)
                Qcat[(size_t)(rowb + r) * 1024 + col] = (bf16_t)(acc[mt][nt][r] + bv);
        }
    }
}

__global__ __launch_bounds__(256) void k_kvgemm(
    const bf16_t* __restrict__ Qcat,
    const float* __restrict__ Wfk, const float* __restrict__ bfk,
    const float* __restrict__ Wfv, const float* __restrict__ bfv,
    bf16_t* __restrict__ Kf, bf16_t* __restrict__ Vt)
{
    __shared__ __attribute__((aligned(16))) union {
        struct { bf16_t Al[128 * 32]; bf16_t Bl[128 * 32]; } g;
        bf16_t T[128 * 132];
    } sm;
    const int m0 = blockIdx.x * 128;
    const int n0 = blockIdx.y * 128;
    const bool isV = (n0 >= 512);
    const float* W    = isV ? Wfv : Wfk;
    const float* bias = isV ? bfv : bfk;
    const int nw = n0 & 511;
    const int t    = threadIdx.x;
    const int lane = t & 63;
    const int wv   = t >> 6;
    const int wm   = (wv & 1) * 64;
    const int wn   = (wv >> 1) * 64;
    const int l15  = lane & 15;
    const int quad = lane >> 4;

    const int ar0 = t >> 2,          ac0 = (t & 3) * 8;
    const int ar1 = (256 + t) >> 2,  ac1 = ((256 + t) & 3) * 8;

    f32x4 acc[4][4] = {};

    for (int k0 = 0; k0 < 1024; k0 += 32) {
        __syncthreads();
        load_lds16(Qcat + (size_t)(m0 + ar0) * 1024 + k0 + ac0, sm.g.Al + t * 8);
        load_lds16(Qcat + (size_t)(m0 + ar1) * 1024 + k0 + ac1, sm.g.Al + (256 + t) * 8);
#pragma unroll
        for (int p = 0; p < 4; ++p) {
            const int lin = p * 256 + t;
            const int row = lin >> 3;
            const int ch  = (lin & 7) * 4;
            const float4 vb = *(const float4*)(W + (size_t)(nw + row) * 1024 + k0 + ch);
            bf16x4 pb = { (bf16_t)vb.x, (bf16_t)vb.y, (bf16_t)vb.z, (bf16_t)vb.w };
            *(bf16x4*)(sm.g.Bl + row * 32 + ch) = pb;
        }
        __syncthreads();
        bf16x8 af[4], bfr[4];
#pragma unroll
        for (int i = 0; i < 4; ++i)
            af[i] = *(const bf16x8*)(sm.g.Al + (wm + i * 16 + l15) * 32 + quad * 8);
#pragma unroll
        for (int i = 0; i < 4; ++i)
            bfr[i] = *(const bf16x8*)(sm.g.Bl + (wn + i * 16 + l15) * 32 + quad * 8);
#pragma unroll
        for (int mt = 0; mt < 4; ++mt)
#pragma unroll
            for (int nt = 0; nt < 4; ++nt)
                acc[mt][nt] = mfma16(af[mt], bfr[nt], acc[mt][nt]);
    }

    if (!isV) {
#pragma unroll
        for (int nt = 0; nt < 4; ++nt) {
            const int col  = n0 + wn + nt * 16 + l15;
            const float bv = bias[col];
#pragma unroll
            for (int mt = 0; mt < 4; ++mt) {
                const int rowb = m0 + wm + mt * 16 + quad * 4;
#pragma unroll
                for (int r = 0; r < 4; ++r)
                    Kf[(size_t)(rowb + r) * 512 + col] = (bf16_t)(acc[mt][nt][r] + bv);
            }
        }
    } else {
        __syncthreads();
#pragma unroll
        for (int nt = 0; nt < 4; ++nt) {
            const int dl = wn + nt * 16 + l15;
            const float bv = bias[nw + dl];
#pragma unroll
            for (int mt = 0; mt < 4; ++mt) {
                const int sl = wm + mt * 16 + quad * 4;
#pragma unroll
                for (int r = 0; r < 4; ++r)
                    sm.T[dl * 132 + sl + r] = (bf16_t)(acc[mt][nt][r] + bv);
            }
        }
        __syncthreads();
        const int bb = m0 >> 11;
        const int sb = m0 & 2047;
        const int half = lane >> 5;
        const int sl4  = (lane & 31) * 4;
#pragma unroll
        for (int i = 0; i < 16; ++i) {
            const int dl = wv * 32 + i * 2 + half;
            const bf16x4 v = *(const bf16x4*)(sm.T + dl * 132 + sl4);
            *(bf16x4*)(Vt + (size_t)(bb * 512 + nw + dl) * 2048 + sb + sl4) = v;
        }
    }
}

// ---------------------------------------------------------------------------
// k3: attention (proven 241 µs body; mode 0 -> bf16 attn buffers)
// ---------------------------------------------------------------------------
__global__ __launch_bounds__(256, 2) void k_attn(
    const bf16_t* __restrict__ Qcat, const bf16_t* __restrict__ Kf,
    const bf16_t* __restrict__ Vt,
    const float* __restrict__ X, const float* __restrict__ Y,
    float* __restrict__ out, bf16_t* __restrict__ attn,
    const int mode, const int which)
{
    __shared__ __attribute__((aligned(16))) bf16_t Kl[2][32 * 520];
    __shared__ __attribute__((aligned(16))) bf16_t Pl[2][64 * 40];
    __shared__ float lsumL[64];

    const int b = blockIdx.y;
    const int w = (mode == 0) ? (int)blockIdx.z : which;
    const int t    = threadIdx.x;
    const int lane = t & 63;
    const int wv   = t >> 6;
    const int l15  = lane & 15;
    const int quad = lane >> 4;
    const int q0   = blockIdx.x * 64;
    const int qw   = q0 + wv * 16;

    const bf16_t* Kbase = Kf + (size_t)b * S_ * 512;
    const bf16_t* Vbase = Vt + ((size_t)b * 512 + wv * 128) * S_;

    bf16x8 aq[16];
    {
        const bf16_t* qp = Qcat + (size_t)(b * S_ + qw + l15) * 1024 + w * 512 + quad * 8;
#pragma unroll
        for (int ks = 0; ks < 16; ++ks) aq[ks] = *(const bf16x8*)(qp + ks * 32);
    }

    f32x4 acc[4][8] = {};
    float lacc[4] = { 0.f, 0.f, 0.f, 0.f };
    const float sc2 = 0.04419417382415922f * 1.4426950408889634f;

    // ---- prologue: K0 -> Kl[0]
#pragma unroll
    for (int p = 0; p < 8; ++p) {
        const int row = wv * 8 + p;
        load_lds16(Kbase + (size_t)row * 512 + lane * 8, Kl[0] + row * 520);
    }
    __syncthreads();

    // ---- peeled iter 0
    {
#pragma unroll
        for (int p = 0; p < 8; ++p) {
            const int row = wv * 8 + p;
            load_lds16(Kbase + (size_t)(32 + row) * 512 + lane * 8, Kl[1] + row * 520);
        }
        f32x4 s0a = {}, s0b = {}, s1a = {}, s1b = {};
#pragma unroll
        for (int ks = 0; ks < 16; ks += 2) {
            const bf16x8 b0 = *(const bf16x8*)(Kl[0] + l15 * 520 + ks * 32 + quad * 8);
            const bf16x8 b1 = *(const bf16x8*)(Kl[0] + (16 + l15) * 520 + ks * 32 + quad * 8);
            const bf16x8 c0 = *(const bf16x8*)(Kl[0] + l15 * 520 + (ks + 1) * 32 + quad * 8);
            const bf16x8 c1 = *(const bf16x8*)(Kl[0] + (16 + l15) * 520 + (ks + 1) * 32 + quad * 8);
            s0a = mfma16(aq[ks], b0, s0a);
            s1a = mfma16(aq[ks], b1, s1a);
            s0b = mfma16(aq[ks + 1], c0, s0b);
            s1b = mfma16(aq[ks + 1], c1, s1b);
        }
        const f32x4 sA = s0a + s0b, sB = s1a + s1b;
#pragma unroll
        for (int r = 0; r < 4; ++r) {
            const float p0 = exp2f(sA[r] * sc2);
            const float p1 = exp2f(sB[r] * sc2);
            lacc[r] += p0 + p1;
            Pl[0][(wv * 16 + quad * 4 + r) * 40 + l15] = (bf16_t)p0;
            Pl[0][(wv * 16 + quad * 4 + r) * 40 + 16 + l15] = (bf16_t)p1;
        }
        __syncthreads();
    }

    // ---- main loop kb = 1..63
    for (int kb = 1; kb < 64; ++kb) {
        const int cur = kb & 1;
        const int prv = cur ^ 1;

        bf16x8 vb[8];
#pragma unroll
        for (int i = 0; i < 8; ++i)
            vb[i] = *(const bf16x8*)(Vbase + (size_t)(i * 16 + l15) * S_ +
                                     (kb - 1) * 32 + quad * 8);

        {
            const bf16_t* src = Kbase + (size_t)(kb + 1) * 32 * 512;
#pragma unroll
            for (int p = 0; p < 8; ++p) {
                const int row = wv * 8 + p;
                load_lds16(src + (size_t)row * 512 + lane * 8, Kl[prv] + row * 520);
            }
        }

        f32x4 s0a = {}, s0b = {}, s1a = {}, s1b = {};
#pragma unroll
        for (int ks = 0; ks < 16; ks += 2) {
            const bf16x8 b0 = *(const bf16x8*)(Kl[cur] + l15 * 520 + ks * 32 + quad * 8);
            const bf16x8 b1 = *(const bf16x8*)(Kl[cur] + (16 + l15) * 520 + ks * 32 + quad * 8);
            const bf16x8 c0 = *(const bf16x8*)(Kl[cur] + l15 * 520 + (ks + 1) * 32 + quad * 8);
            const bf16x8 c1 = *(const bf16x8*)(Kl[cur] + (16 + l15) * 520 + (ks + 1) * 32 + quad * 8);
            s0a = mfma16(aq[ks], b0, s0a);
            s1a = mfma16(aq[ks], b1, s1a);
            s0b = mfma16(aq[ks + 1], c0, s0b);
            s1b = mfma16(aq[ks + 1], c1, s1b);
        }

        {
            bf16x8 ap[4];
#pragma unroll
            for (int qt = 0; qt < 4; ++qt)
                ap[qt] = *(const bf16x8*)(Pl[prv] + (qt * 16 + l15) * 40 + quad * 8);
#pragma unroll
            for (int dt = 0; dt < 8; ++dt)
#pragma unroll
                for (int qt = 0; qt < 4; ++qt)
                    acc[qt][dt] = mfma16(ap[qt], vb[dt], acc[qt][dt]);
        }

        const f32x4 sA = s0a + s0b, sB = s1a + s1b;
#pragma unroll
        for (int r = 0; r < 4; ++r) {
            const float p0 = exp2f(sA[r] * sc2);
            const float p1 = exp2f(sB[r] * sc2);
            lacc[r] += p0 + p1;
            Pl[cur][(wv * 16 + quad * 4 + r) * 40 + l15] = (bf16_t)p0;
            Pl[cur][(wv * 16 + quad * 4 + r) * 40 + 16 + l15] = (bf16_t)p1;
        }

        __syncthreads();
    }

    // ---- epilogue: PV(63) from Pl[1]
    {
        bf16x8 vb[8];
#pragma unroll
        for (int i = 0; i < 8; ++i)
            vb[i] = *(const bf16x8*)(Vbase + (size_t)(i * 16 + l15) * S_ +
                                     63 * 32 + quad * 8);
        bf16x8 ap[4];
#pragma unroll
        for (int qt = 0; qt < 4; ++qt)
            ap[qt] = *(const bf16x8*)(Pl[1] + (qt * 16 + l15) * 40 + quad * 8);
#pragma unroll
        for (int dt = 0; dt < 8; ++dt)
#pragma unroll
            for (int qt = 0; qt < 4; ++qt)
                acc[qt][dt] = mfma16(ap[qt], vb[dt], acc[qt][dt]);
    }

    {
        float lrow[4];
#pragma unroll
        for (int r = 0; r < 4; ++r) {
            float v = lacc[r];
#pragma unroll
            for (int off = 1; off < 16; off <<= 1) v += __shfl_xor(v, off, 64);
            lrow[r] = v;
        }
        if (l15 == 0) {
#pragma unroll
            for (int r = 0; r < 4; ++r) lsumL[wv * 16 + quad * 4 + r] = lrow[r];
        }
    }
    __syncthreads();

#pragma unroll
    for (int qt = 0; qt < 4; ++qt) {
        f32x4 inv;
#pragma unroll
        for (int r = 0; r < 4; ++r) inv[r] = 1.0f / lsumL[qt * 16 + quad * 4 + r];
#pragma unroll
        for (int dt = 0; dt < 8; ++dt) {
            const int d = wv * 128 + dt * 16 + l15;
#pragma unroll
            for (int r = 0; r < 4; ++r) {
                const float v = acc[qt][dt][r] * inv[r];
                const size_t idx =
                    (size_t)(b * S_ + q0 + qt * 16 + quad * 4 + r) * 512 + d;
                if (mode == 0)      attn[(size_t)w * M_TOT * 512 + idx] = (bf16_t)v;
                else if (mode == 1) out[idx] = X[idx] + Y[idx] + v;
                else                out[idx] += v;
            }
        }
    }
}

// ---------------------------------------------------------------------------
// k4: out = X + Y + attn0 + attn1
// ---------------------------------------------------------------------------
__global__ __launch_bounds__(256) void k_add(
    const float* __restrict__ X, const float* __restrict__ Y,
    const bf16_t* __restrict__ a0, const bf16_t* __restrict__ a1,
    float* __restrict__ out)
{
    const size_t i = ((size_t)blockIdx.x * 256 + threadIdx.x) * 4;
    const float4 x = *(const float4*)(X + i);
    const float4 y = *(const float4*)(Y + i);
    const bf16x4 v0 = *(const bf16x4*)(a0 + i);
    const bf16x4 v1 = *(const bf16x4*)(a1 + i);
    float4 o;
    o.x = x.x + y.x + (float)v0[0] + (float)v1[0];
    o.y = x.y + y.y + (float)v0[1] + (float)v1[1];
    o.z = x.z + y.z + (float)v0[2] + (float)v1[2];
    o.w = x.w + y.w + (float)v0[3] + (float)v1[3];
    *(float4*)(out + i) = o;
}

extern "C" void kernel_launch(void* const* d_in, const int* in_sizes, int n_in,
                              void* d_out, int out_size, void* d_ws, size_t ws_size,
                              hipStream_t stream)
{
    const float* X   = (const float*)d_in[0];
    const float* Y   = (const float*)d_in[1];
    const float* Wxq = (const float*)d_in[2];
    const float* bxq = (const float*)d_in[3];
    const float* Wyq = (const float*)d_in[4];
    const float* byq = (const float*)d_in[5];
    const float* Wfk = (const float*)d_in[6];
    const float* bfk = (const float*)d_in[7];
    const float* Wfv = (const float*)d_in[8];
    const float* bfv = (const float*)d_in[9];
    float* out = (float*)d_out;
    char*  ws  = (char*)d_ws;

    // ws: Qcat 0-32M | Kf 32-48M (Yb alias) | Vt 48-64M |
    //     Wb 64-67M / attn0 64-80M | Xb / attn1 80-96M
    bf16_t* Qcat = (bf16_t*)(ws);
    bf16_t* Kf   = (bf16_t*)(ws + (size_t)33554432);
    bf16_t* Vt   = (bf16_t*)(ws + (size_t)50331648);
    bf16_t* Wb   = (bf16_t*)(ws + (size_t)67108864);  // dead after k2
    bf16_t* attn = (bf16_t*)(ws + (size_t)67108864);  // attn0 @64M, attn1 @80M
    bf16_t* Xb   = (bf16_t*)(ws + (size_t)83886080);  // dead after k1
    bf16_t* Yb   = Kf;                                // dead before k2 writes Kf
    const bool big = ws_size >= (size_t)100663296;

    if (big) {
        k_cvt<<<dim3(2048), 256, 0, stream>>>(X, Y, Xb, Yb);
        k_cvtw<<<dim3(1536), 256, 0, stream>>>(Wxq, Wyq, Wfk, Wfv, Wb);
        k_qgemm_bb<<<dim3(128, 8), 256, 0, stream>>>(Xb, Yb, Wb, bxq, byq, Qcat);
        k_kvgemm_bb<<<dim3(128, 8), 256, 0, stream>>>(Qcat, Wb + 524288, bfk,
                                                      Wb + 1048576, bfv, Kf, Vt);
        k_attn<<<dim3(32, 8, 2), 256, 0, stream>>>(Qcat, Kf, Vt, X, Y, out, attn, 0, 0);
        k_add<<<dim3(8192), 256, 0, stream>>>(X, Y, attn, attn + (size_t)M_TOT * 512, out);
    } else {
        k_qgemm<<<dim3(128, 8), 256, 0, stream>>>(X, Y, Wxq, bxq, Wyq, byq, Qcat);
        k_kvgemm<<<dim3(128, 8), 256, 0, stream>>>(Qcat, Wfk, bfk, Wfv, bfv, Kf, Vt);
        k_attn<<<dim3(32, 8, 1), 256, 0, stream>>>(Qcat, Kf, Vt, X, Y, out, attn, 1, 0);
        k_attn<<<dim3(32, 8, 1), 256, 0, stream>>>(Qcat, Kf, Vt, X, Y, out, attn, 2, 1);
    }
}

// Round 11
// 438.455 us; speedup vs baseline: 1.3731x; 1.0081x over previous
//
#include <hip/hip_runtime.h>

// ---------------------------------------------------------------------------
// CA2_82300163326041: dual cross-attention fusion, MI355X bf16-MFMA pipeline.
// R10: two safe levers on the non-attn 203 µs:
//  (1) GEMM grid order swapped to dim3(n, m) — x (n) fastest. Consecutive
//      blocks now share the A-tile, so A streams HBM ONCE (32 MB) instead of
//      once per n-block (256 MB kvgemm / 128 MB qgemm); W (1-2 MB) turns
//      L2-resident. Pure index remap, no correctness surface.
//  (2) k_cvtw merged into k_cvt (one launch fewer).
// attn untouched: proven 239 µs body (R2/R3/R6/R7/R8 levers all neutral or
// worse; occupancy register-capped at 2 waves/SIMD: 128 VGPR + 128 AGPR).
//   k_cvt  : X,Y -> bf16 + weights -> bf16 concat (merged)
//   k_qgemm_bb : Qcat = [Xb|Yb]@[Wxqb|Wyqb]^T + bias, both operands DMA
//   k_kvgemm_bb: Kf, Vt (transposed V), both operands DMA
//   k_attn : mode 0 -> attn0/attn1 (bf16)
//   k_add  : out = X + Y + attn0 + attn1
// ws: Qcat 0-32M | Kf 32-48M (Yb alias pre-k2) | Vt 48-64M |
//     Wb 64-67M / attn0 64-80M (Wb dead after k2) | Xb / attn1 80-96M
// MFMA layouts (measured, guide §3): A[m=lane&15][k=quad*8+j],
// Bt[n=lane&15][k=quad*8+j], D: col=lane&15, row=quad*4+reg.
// ---------------------------------------------------------------------------

#define B_    8
#define S_    2048
#define D_    512
#define M_TOT (B_ * S_) /* 16384 */

typedef __bf16 bf16_t;
typedef __bf16 bf16x8 __attribute__((ext_vector_type(8)));
typedef __bf16 bf16x4 __attribute__((ext_vector_type(4)));
typedef float  f32x4  __attribute__((ext_vector_type(4)));

typedef __attribute__((address_space(1))) const void* gas_cv;
typedef __attribute__((address_space(3))) void*       las_v;

__device__ __forceinline__ f32x4 mfma16(bf16x8 a, bf16x8 b, f32x4 c) {
    return __builtin_amdgcn_mfma_f32_16x16x32_bf16(a, b, c, 0, 0, 0);
}
__device__ __forceinline__ void load_lds16(const void* g, void* l) {
    __builtin_amdgcn_global_load_lds((gas_cv)g, (las_v)l, 16, 0, 0);
}

// ---------------------------------------------------------------------------
// k_cvt: X,Y fp32 -> bf16 AND weights fp32 -> bf16 concat (merged k_cvtw).
// Wb layout (elems): [Wxqb 256K | Wyqb 256K | Wfkb 512K | Wfvb 512K].
// ---------------------------------------------------------------------------
__global__ __launch_bounds__(256) void k_cvt(
    const float* __restrict__ X, const float* __restrict__ Y,
    const float* __restrict__ Wxq, const float* __restrict__ Wyq,
    const float* __restrict__ Wfk, const float* __restrict__ Wfv,
    bf16_t* __restrict__ Xb, bf16_t* __restrict__ Yb,
    bf16_t* __restrict__ Wb)
{
    const int tid = blockIdx.x * 256 + threadIdx.x;   // grid 2048 -> 524288
    const int n4 = M_TOT * 512 / 4;
    for (int i = tid; i < n4; i += 2048 * 256) {
        const float4 x = *(const float4*)(X + (size_t)i * 4);
        bf16x4 px = { (bf16_t)x.x, (bf16_t)x.y, (bf16_t)x.z, (bf16_t)x.w };
        *(bf16x4*)(Xb + (size_t)i * 4) = px;
        const float4 y = *(const float4*)(Y + (size_t)i * 4);
        bf16x4 py = { (bf16_t)y.x, (bf16_t)y.y, (bf16_t)y.z, (bf16_t)y.w };
        *(bf16x4*)(Yb + (size_t)i * 4) = py;
    }
    if (tid < 393216) {                                // weight float4s
        const float* src; int sj;
        if (tid < 65536)       { src = Wxq; sj = tid; }
        else if (tid < 131072) { src = Wyq; sj = tid - 65536; }
        else if (tid < 262144) { src = Wfk; sj = tid - 131072; }
        else                   { src = Wfv; sj = tid - 262144; }
        const float4 v = *(const float4*)(src + (size_t)sj * 4);
        bf16x4 p = { (bf16_t)v.x, (bf16_t)v.y, (bf16_t)v.z, (bf16_t)v.w };
        *(bf16x4*)(Wb + (size_t)tid * 4) = p;
    }
}

// ---------------------------------------------------------------------------
// k_qgemm_bb: Qcat = [Xb|Yb] @ [Wxqb|Wyqb]^T + bias. K=512. Both operands
// bf16 DMA into linear [128][32] LDS. GRID: dim3(n=8, m=128) — x fastest is
// n, so consecutive blocks share the A-tile (A streams HBM once).
// ---------------------------------------------------------------------------
__global__ __launch_bounds__(256) void k_qgemm_bb(
    const bf16_t* __restrict__ Xb, const bf16_t* __restrict__ Yb,
    const bf16_t* __restrict__ Wb,
    const float* __restrict__ bxq, const float* __restrict__ byq,
    bf16_t* __restrict__ Qcat)
{
    __shared__ __attribute__((aligned(16))) bf16_t Al[128 * 32];
    __shared__ __attribute__((aligned(16))) bf16_t Bl[128 * 32];
    const int m0 = blockIdx.y * 128;
    const int n0 = blockIdx.x * 128;           // N = 1024 (Q1 | Q2)
    const bool second = (n0 >= 512);
    const bf16_t* A   = second ? Yb : Xb;
    const bf16_t* W   = Wb + (second ? 262144 : 0);
    const float* bias = second ? byq : bxq;
    const int nw = n0 & 511;
    const int t    = threadIdx.x;
    const int lane = t & 63;
    const int wv   = t >> 6;
    const int wm   = (wv & 1) * 64;
    const int wn   = (wv >> 1) * 64;
    const int l15  = lane & 15;
    const int quad = lane >> 4;

    const int ar0 = t >> 2,          ac0 = (t & 3) * 8;
    const int ar1 = (256 + t) >> 2,  ac1 = ((256 + t) & 3) * 8;

    f32x4 acc[4][4] = {};

    for (int k0 = 0; k0 < 512; k0 += 32) {
        __syncthreads();
        load_lds16(A + (size_t)(m0 + ar0) * 512 + k0 + ac0, Al + t * 8);
        load_lds16(A + (size_t)(m0 + ar1) * 512 + k0 + ac1, Al + (256 + t) * 8);
        load_lds16(W + (size_t)(nw + ar0) * 512 + k0 + ac0, Bl + t * 8);
        load_lds16(W + (size_t)(nw + ar1) * 512 + k0 + ac1, Bl + (256 + t) * 8);
        __syncthreads();
        bf16x8 af[4], bfr[4];
#pragma unroll
        for (int i = 0; i < 4; ++i)
            af[i] = *(const bf16x8*)(Al + (wm + i * 16 + l15) * 32 + quad * 8);
#pragma unroll
        for (int i = 0; i < 4; ++i)
            bfr[i] = *(const bf16x8*)(Bl + (wn + i * 16 + l15) * 32 + quad * 8);
#pragma unroll
        for (int mt = 0; mt < 4; ++mt)
#pragma unroll
            for (int nt = 0; nt < 4; ++nt)
                acc[mt][nt] = mfma16(af[mt], bfr[nt], acc[mt][nt]);
    }

#pragma unroll
    for (int nt = 0; nt < 4; ++nt) {
        const int col  = n0 + wn + nt * 16 + l15;
        const float bv = bias[col & 511];
#pragma unroll
        for (int mt = 0; mt < 4; ++mt) {
            const int rowb = m0 + wm + mt * 16 + quad * 4;
#pragma unroll
            for (int r = 0; r < 4; ++r)
                Qcat[(size_t)(rowb + r) * 1024 + col] = (bf16_t)(acc[mt][nt][r] + bv);
        }
    }
}

// ---------------------------------------------------------------------------
// k_kvgemm_bb: [Kf | Vf] = Qcat @ [Wfkb | Wfvb]^T + bias. K=1024. Both
// operands bf16 DMA. GRID: dim3(n=8, m=128) — A-tile shared by consecutive
// blocks. Vf stored TRANSPOSED per batch Vt[b][d][s] via LDS.
// ---------------------------------------------------------------------------
__global__ __launch_bounds__(256) void k_kvgemm_bb(
    const bf16_t* __restrict__ Qcat,
    const bf16_t* __restrict__ Wfkb, const float* __restrict__ bfk,
    const bf16_t* __restrict__ Wfvb, const float* __restrict__ bfv,
    bf16_t* __restrict__ Kf, bf16_t* __restrict__ Vt)
{
    __shared__ __attribute__((aligned(16))) union {
        struct { bf16_t Al[128 * 32]; bf16_t Bl[128 * 32]; } g;
        bf16_t T[128 * 132];   // [d_local][s_local], pad 128->132
    } sm;
    const int m0 = blockIdx.y * 128;
    const int n0 = blockIdx.x * 128;           // N = 1024 (Kf | Vf)
    const bool isV = (n0 >= 512);
    const bf16_t* W   = isV ? Wfvb : Wfkb;
    const float* bias = isV ? bfv : bfk;
    const int nw = n0 & 511;
    const int t    = threadIdx.x;
    const int lane = t & 63;
    const int wv   = t >> 6;
    const int wm   = (wv & 1) * 64;
    const int wn   = (wv >> 1) * 64;
    const int l15  = lane & 15;
    const int quad = lane >> 4;

    const int ar0 = t >> 2,          ac0 = (t & 3) * 8;
    const int ar1 = (256 + t) >> 2,  ac1 = ((256 + t) & 3) * 8;

    f32x4 acc[4][4] = {};

    for (int k0 = 0; k0 < 1024; k0 += 32) {
        __syncthreads();
        load_lds16(Qcat + (size_t)(m0 + ar0) * 1024 + k0 + ac0, sm.g.Al + t * 8);
        load_lds16(Qcat + (size_t)(m0 + ar1) * 1024 + k0 + ac1, sm.g.Al + (256 + t) * 8);
        load_lds16(W + (size_t)(nw + ar0) * 1024 + k0 + ac0, sm.g.Bl + t * 8);
        load_lds16(W + (size_t)(nw + ar1) * 1024 + k0 + ac1, sm.g.Bl + (256 + t) * 8);
        __syncthreads();
        bf16x8 af[4], bfr[4];
#pragma unroll
        for (int i = 0; i < 4; ++i)
            af[i] = *(const bf16x8*)(sm.g.Al + (wm + i * 16 + l15) * 32 + quad * 8);
#pragma unroll
        for (int i = 0; i < 4; ++i)
            bfr[i] = *(const bf16x8*)(sm.g.Bl + (wn + i * 16 + l15) * 32 + quad * 8);
#pragma unroll
        for (int mt = 0; mt < 4; ++mt)
#pragma unroll
            for (int nt = 0; nt < 4; ++nt)
                acc[mt][nt] = mfma16(af[mt], bfr[nt], acc[mt][nt]);
    }

    if (!isV) {
#pragma unroll
        for (int nt = 0; nt < 4; ++nt) {
            const int col  = n0 + wn + nt * 16 + l15;   // < 512
            const float bv = bias[col];
#pragma unroll
            for (int mt = 0; mt < 4; ++mt) {
                const int rowb = m0 + wm + mt * 16 + quad * 4;
#pragma unroll
                for (int r = 0; r < 4; ++r)
                    Kf[(size_t)(rowb + r) * 512 + col] = (bf16_t)(acc[mt][nt][r] + bv);
            }
        }
    } else {
        __syncthreads();   // staging reads of the last k-block are done
#pragma unroll
        for (int nt = 0; nt < 4; ++nt) {
            const int dl = wn + nt * 16 + l15;
            const float bv = bias[nw + dl];
#pragma unroll
            for (int mt = 0; mt < 4; ++mt) {
                const int sl = wm + mt * 16 + quad * 4;
#pragma unroll
                for (int r = 0; r < 4; ++r)
                    sm.T[dl * 132 + sl + r] = (bf16_t)(acc[mt][nt][r] + bv);
            }
        }
        __syncthreads();
        const int bb = m0 >> 11;             // batch
        const int sb = m0 & 2047;
        const int half = lane >> 5;
        const int sl4  = (lane & 31) * 4;
#pragma unroll
        for (int i = 0; i < 16; ++i) {
            const int dl = wv * 32 + i * 2 + half;
            const bf16x4 v = *(const bf16x4*)(sm.T + dl * 132 + sl4);
            *(bf16x4*)(Vt + (size_t)(bb * 512 + nw + dl) * 2048 + sb + sl4) = v;
        }
    }
}

// ---------------------------------------------------------------------------
// legacy k1/k2 (fp32 reg-staged) for the small-ws fallback path
// ---------------------------------------------------------------------------
__global__ __launch_bounds__(256) void k_qgemm(
    const float* __restrict__ X, const float* __restrict__ Y,
    const float* __restrict__ Wxq, const float* __restrict__ bxq,
    const float* __restrict__ Wyq, const float* __restrict__ byq,
    bf16_t* __restrict__ Qcat)
{
    __shared__ __attribute__((aligned(16))) bf16_t Al[128 * 40];
    __shared__ __attribute__((aligned(16))) bf16_t Bl[128 * 40];
    const int m0 = blockIdx.x * 128;
    const int n0 = blockIdx.y * 128;
    const bool second = (n0 >= 512);
    const float* A    = second ? Y : X;
    const float* W    = second ? Wyq : Wxq;
    const float* bias = second ? byq : bxq;
    const int nw = n0 & 511;
    const int t    = threadIdx.x;
    const int lane = t & 63;
    const int wv   = t >> 6;
    const int wm   = (wv & 1) * 64;
    const int wn   = (wv >> 1) * 64;
    const int l15  = lane & 15;
    const int quad = lane >> 4;

    f32x4 acc[4][4] = {};

    for (int k0 = 0; k0 < 512; k0 += 32) {
        __syncthreads();
#pragma unroll
        for (int p = 0; p < 4; ++p) {
            const int lin = p * 256 + t;
            const int row = lin >> 3;
            const int ch  = (lin & 7) * 4;
            const float4 va = *(const float4*)(A + (size_t)(m0 + row) * 512 + k0 + ch);
            bf16x4 pa = { (bf16_t)va.x, (bf16_t)va.y, (bf16_t)va.z, (bf16_t)va.w };
            *(bf16x4*)(Al + row * 40 + ch) = pa;
            const float4 vb = *(const float4*)(W + (size_t)(nw + row) * 512 + k0 + ch);
            bf16x4 pb = { (bf16_t)vb.x, (bf16_t)vb.y, (bf16_t)vb.z, (bf16_t)vb.w };
            *(bf16x4*)(Bl + row * 40 + ch) = pb;
        }
        __syncthreads();
        bf16x8 af[4], bfr[4];
#pragma unroll
        for (int i = 0; i < 4; ++i)
            af[i] = *(const bf16x8*)(Al + (wm + i * 16 + l15) * 40 + quad * 8);
#pragma unroll
        for (int i = 0; i < 4; ++i)
            bfr[i] = *(const bf16x8*)(Bl + (wn + i * 16 + l15) * 40 + quad * 8);
#pragma unroll
        for (int mt = 0; mt < 4; ++mt)
#pragma unroll
            for (int nt = 0; nt < 4; ++nt)
                acc[mt][nt] = mfma16(af[mt], bfr[nt], acc[mt][nt]);
    }

#pragma unroll
    for (int nt = 0; nt < 4; ++nt) {
        const int col  = n0 + wn + nt * 16 + l15;
        const float bv = bias[col & 511];
#pragma unroll
        for (int mt = 0; mt < 4; ++mt) {
            const int rowb = m0 + wm + mt * 16 + quad * 4;
#pragma unroll
            for (int r = 0; r < 4; ++r)
                Qcat[(size_t)(rowb + r) * 1024 + col] = (bf16_t)(acc[mt][nt][r] + bv);
        }
    }
}

__global__ __launch_bounds__(256) void k_kvgemm(
    const bf16_t* __restrict__ Qcat,
    const float* __restrict__ Wfk, const float* __restrict__ bfk,
    const float* __restrict__ Wfv, const float* __restrict__ bfv,
    bf16_t* __restrict__ Kf, bf16_t* __restrict__ Vt)
{
    __shared__ __attribute__((aligned(16))) union {
        struct { bf16_t Al[128 * 32]; bf16_t Bl[128 * 32]; } g;
        bf16_t T[128 * 132];
    } sm;
    const int m0 = blockIdx.x * 128;
    const int n0 = blockIdx.y * 128;
    const bool isV = (n0 >= 512);
    const float* W    = isV ? Wfv : Wfk;
    const float* bias = isV ? bfv : bfk;
    const int nw = n0 & 511;
    const int t    = threadIdx.x;
    const int lane = t & 63;
    const int wv   = t >> 6;
    const int wm   = (wv & 1) * 64;
    const int wn   = (wv >> 1) * 64;
    const int l15  = lane & 15;
    const int quad = lane >> 4;

    const int ar0 = t >> 2,          ac0 = (t & 3) * 8;
    const int ar1 = (256 + t) >> 2,  ac1 = ((256 + t) & 3) * 8;

    f32x4 acc[4][4] = {};

    for (int k0 = 0; k0 < 1024; k0 += 32) {
        __syncthreads();
        load_lds16(Qcat + (size_t)(m0 + ar0) * 1024 + k0 + ac0, sm.g.Al + t * 8);
        load_lds16(Qcat + (size_t)(m0 + ar1) * 1024 + k0 + ac1, sm.g.Al + (256 + t) * 8);
#pragma unroll
        for (int p = 0; p < 4; ++p) {
            const int lin = p * 256 + t;
            const int row = lin >> 3;
            const int ch  = (lin & 7) * 4;
            const float4 vb = *(const float4*)(W + (size_t)(nw + row) * 1024 + k0 + ch);
            bf16x4 pb = { (bf16_t)vb.x, (bf16_t)vb.y, (bf16_t)vb.z, (bf16_t)vb.w };
            *(bf16x4*)(sm.g.Bl + row * 32 + ch) = pb;
        }
        __syncthreads();
        bf16x8 af[4], bfr[4];
#pragma unroll
        for (int i = 0; i < 4; ++i)
            af[i] = *(const bf16x8*)(sm.g.Al + (wm + i * 16 + l15) * 32 + quad * 8);
#pragma unroll
        for (int i = 0; i < 4; ++i)
            bfr[i] = *(const bf16x8*)(sm.g.Bl + (wn + i * 16 + l15) * 32 + quad * 8);
#pragma unroll
        for (int mt = 0; mt < 4; ++mt)
#pragma unroll
            for (int nt = 0; nt < 4; ++nt)
                acc[mt][nt] = mfma16(af[mt], bfr[nt], acc[mt][nt]);
    }

    if (!isV) {
#pragma unroll
        for (int nt = 0; nt < 4; ++nt) {
            const int col  = n0 + wn + nt * 16 + l15;
            const float bv = bias[col];
#pragma unroll
            for (int mt = 0; mt < 4; ++mt) {
                const int rowb = m0 + wm + mt * 16 + quad * 4;
#pragma unroll
                for (int r = 0; r < 4; ++r)
                    Kf[(size_t)(rowb + r) * 512 + col] = (bf16_t)(acc[mt][nt][r] + bv);
            }
        }
    } else {
        __syncthreads();
#pragma unroll
        for (int nt = 0; nt < 4; ++nt) {
            const int dl = wn + nt * 16 + l15;
            const float bv = bias[nw + dl];
#pragma unroll
            for (int mt = 0; mt < 4; ++mt) {
                const int sl = wm + mt * 16 + quad * 4;
#pragma unroll
                for (int r = 0; r < 4; ++r)
                    sm.T[dl * 132 + sl + r] = (bf16_t)(acc[mt][nt][r] + bv);
            }
        }
        __syncthreads();
        const int bb = m0 >> 11;
        const int sb = m0 & 2047;
        const int half = lane >> 5;
        const int sl4  = (lane & 31) * 4;
#pragma unroll
        for (int i = 0; i < 16; ++i) {
            const int dl = wv * 32 + i * 2 + half;
            const bf16x4 v = *(const bf16x4*)(sm.T + dl * 132 + sl4);
            *(bf16x4*)(Vt + (size_t)(bb * 512 + nw + dl) * 2048 + sb + sl4) = v;
        }
    }
}

// ---------------------------------------------------------------------------
// k3: attention (proven 239 µs body; mode 0 -> bf16 attn buffers)
// ---------------------------------------------------------------------------
__global__ __launch_bounds__(256, 2) void k_attn(
    const bf16_t* __restrict__ Qcat, const bf16_t* __restrict__ Kf,
    const bf16_t* __restrict__ Vt,
    const float* __restrict__ X, const float* __restrict__ Y,
    float* __restrict__ out, bf16_t* __restrict__ attn,
    const int mode, const int which)
{
    __shared__ __attribute__((aligned(16))) bf16_t Kl[2][32 * 520];
    __shared__ __attribute__((aligned(16))) bf16_t Pl[2][64 * 40];
    __shared__ float lsumL[64];

    const int b = blockIdx.y;
    const int w = (mode == 0) ? (int)blockIdx.z : which;
    const int t    = threadIdx.x;
    const int lane = t & 63;
    const int wv   = t >> 6;
    const int l15  = lane & 15;
    const int quad = lane >> 4;
    const int q0   = blockIdx.x * 64;
    const int qw   = q0 + wv * 16;

    const bf16_t* Kbase = Kf + (size_t)b * S_ * 512;
    const bf16_t* Vbase = Vt + ((size_t)b * 512 + wv * 128) * S_;

    bf16x8 aq[16];
    {
        const bf16_t* qp = Qcat + (size_t)(b * S_ + qw + l15) * 1024 + w * 512 + quad * 8;
#pragma unroll
        for (int ks = 0; ks < 16; ++ks) aq[ks] = *(const bf16x8*)(qp + ks * 32);
    }

    f32x4 acc[4][8] = {};
    float lacc[4] = { 0.f, 0.f, 0.f, 0.f };
    const float sc2 = 0.04419417382415922f * 1.4426950408889634f;

    // ---- prologue: K0 -> Kl[0]
#pragma unroll
    for (int p = 0; p < 8; ++p) {
        const int row = wv * 8 + p;
        load_lds16(Kbase + (size_t)row * 512 + lane * 8, Kl[0] + row * 520);
    }
    __syncthreads();

    // ---- peeled iter 0
    {
#pragma unroll
        for (int p = 0; p < 8; ++p) {
            const int row = wv * 8 + p;
            load_lds16(Kbase + (size_t)(32 + row) * 512 + lane * 8, Kl[1] + row * 520);
        }
        f32x4 s0a = {}, s0b = {}, s1a = {}, s1b = {};
#pragma unroll
        for (int ks = 0; ks < 16; ks += 2) {
            const bf16x8 b0 = *(const bf16x8*)(Kl[0] + l15 * 520 + ks * 32 + quad * 8);
            const bf16x8 b1 = *(const bf16x8*)(Kl[0] + (16 + l15) * 520 + ks * 32 + quad * 8);
            const bf16x8 c0 = *(const bf16x8*)(Kl[0] + l15 * 520 + (ks + 1) * 32 + quad * 8);
            const bf16x8 c1 = *(const bf16x8*)(Kl[0] + (16 + l15) * 520 + (ks + 1) * 32 + quad * 8);
            s0a = mfma16(aq[ks], b0, s0a);
            s1a = mfma16(aq[ks], b1, s1a);
            s0b = mfma16(aq[ks + 1], c0, s0b);
            s1b = mfma16(aq[ks + 1], c1, s1b);
        }
        const f32x4 sA = s0a + s0b, sB = s1a + s1b;
#pragma unroll
        for (int r = 0; r < 4; ++r) {
            const float p0 = exp2f(sA[r] * sc2);
            const float p1 = exp2f(sB[r] * sc2);
            lacc[r] += p0 + p1;
            Pl[0][(wv * 16 + quad * 4 + r) * 40 + l15] = (bf16_t)p0;
            Pl[0][(wv * 16 + quad * 4 + r) * 40 + 16 + l15] = (bf16_t)p1;
        }
        __syncthreads();
    }

    // ---- main loop kb = 1..63
    for (int kb = 1; kb < 64; ++kb) {
        const int cur = kb & 1;
        const int prv = cur ^ 1;

        bf16x8 vb[8];
#pragma unroll
        for (int i = 0; i < 8; ++i)
            vb[i] = *(const bf16x8*)(Vbase + (size_t)(i * 16 + l15) * S_ +
                                     (kb - 1) * 32 + quad * 8);

        {
            const bf16_t* src = Kbase + (size_t)(kb + 1) * 32 * 512;
#pragma unroll
            for (int p = 0; p < 8; ++p) {
                const int row = wv * 8 + p;
                load_lds16(src + (size_t)row * 512 + lane * 8, Kl[prv] + row * 520);
            }
        }

        f32x4 s0a = {}, s0b = {}, s1a = {}, s1b = {};
#pragma unroll
        for (int ks = 0; ks < 16; ks += 2) {
            const bf16x8 b0 = *(const bf16x8*)(Kl[cur] + l15 * 520 + ks * 32 + quad * 8);
            const bf16x8 b1 = *(const bf16x8*)(Kl[cur] + (16 + l15) * 520 + ks * 32 + quad * 8);
            const bf16x8 c0 = *(const bf16x8*)(Kl[cur] + l15 * 520 + (ks + 1) * 32 + quad * 8);
            const bf16x8 c1 = *(const bf16x8*)(Kl[cur] + (16 + l15) * 520 + (ks + 1) * 32 + quad * 8);
            s0a = mfma16(aq[ks], b0, s0a);
            s1a = mfma16(aq[ks], b1, s1a);
            s0b = mfma16(aq[ks + 1], c0, s0b);
            s1b = mfma16(aq[ks + 1], c1, s1b);
        }

        {
            bf16x8 ap[4];
#pragma unroll
            for (int qt = 0; qt < 4; ++qt)
                ap[qt] = *(const bf16x8*)(Pl[prv] + (qt * 16 + l15) * 40 + quad * 8);
#pragma unroll
            for (int dt = 0; dt < 8; ++dt)
#pragma unroll
                for (int qt = 0; qt < 4; ++qt)
                    acc[qt][dt] = mfma16(ap[qt], vb[dt], acc[qt][dt]);
        }

        const f32x4 sA = s0a + s0b, sB = s1a + s1b;
#pragma unroll
        for (int r = 0; r < 4; ++r) {
            const float p0 = exp2f(sA[r] * sc2);
            const float p1 = exp2f(sB[r] * sc2);
            lacc[r] += p0 + p1;
            Pl[cur][(wv * 16 + quad * 4 + r) * 40 + l15] = (bf16_t)p0;
            Pl[cur][(wv * 16 + quad * 4 + r) * 40 + 16 + l15] = (bf16_t)p1;
        }

        __syncthreads();
    }

    // ---- epilogue: PV(63) from Pl[1]
    {
        bf16x8 vb[8];
#pragma unroll
        for (int i = 0; i < 8; ++i)
            vb[i] = *(const bf16x8*)(Vbase + (size_t)(i * 16 + l15) * S_ +
                                     63 * 32 + quad * 8);
        bf16x8 ap[4];
#pragma unroll
        for (int qt = 0; qt < 4; ++qt)
            ap[qt] = *(const bf16x8*)(Pl[1] + (qt * 16 + l15) * 40 + quad * 8);
#pragma unroll
        for (int dt = 0; dt < 8; ++dt)
#pragma unroll
            for (int qt = 0; qt < 4; ++qt)
                acc[qt][dt] = mfma16(ap[qt], vb[dt], acc[qt][dt]);
    }

    {
        float lrow[4];
#pragma unroll
        for (int r = 0; r < 4; ++r) {
            float v = lacc[r];
#pragma unroll
            for (int off = 1; off < 16; off <<= 1) v += __shfl_xor(v, off, 64);
            lrow[r] = v;
        }
        if (l15 == 0) {
#pragma unroll
            for (int r = 0; r < 4; ++r) lsumL[wv * 16 + quad * 4 + r] = lrow[r];
        }
    }
    __syncthreads();

#pragma unroll
    for (int qt = 0; qt < 4; ++qt) {
        f32x4 inv;
#pragma unroll
        for (int r = 0; r < 4; ++r) inv[r] = 1.0f / lsumL[qt * 16 + quad * 4 + r];
#pragma unroll
        for (int dt = 0; dt < 8; ++dt) {
            const int d = wv * 128 + dt * 16 + l15;
#pragma unroll
            for (int r = 0; r < 4; ++r) {
                const float v = acc[qt][dt][r] * inv[r];
                const size_t idx =
                    (size_t)(b * S_ + q0 + qt * 16 + quad * 4 + r) * 512 + d;
                if (mode == 0)      attn[(size_t)w * M_TOT * 512 + idx] = (bf16_t)v;
                else if (mode == 1) out[idx] = X[idx] + Y[idx] + v;
                else                out[idx] += v;
            }
        }
    }
}

// ---------------------------------------------------------------------------
// k4: out = X + Y + attn0 + attn1
// ---------------------------------------------------------------------------
__global__ __launch_bounds__(256) void k_add(
    const float* __restrict__ X, const float* __restrict__ Y,
    const bf16_t* __restrict__ a0, const bf16_t* __restrict__ a1,
    float* __restrict__ out)
{
    const size_t i = ((size_t)blockIdx.x * 256 + threadIdx.x) * 4;
    const float4 x = *(const float4*)(X + i);
    const float4 y = *(const float4*)(Y + i);
    const bf16x4 v0 = *(const bf16x4*)(a0 + i);
    const bf16x4 v1 = *(const bf16x4*)(a1 + i);
    float4 o;
    o.x = x.x + y.x + (float)v0[0] + (float)v1[0];
    o.y = x.y + y.y + (float)v0[1] + (float)v1[1];
    o.z = x.z + y.z + (float)v0[2] + (float)v1[2];
    o.w = x.w + y.w + (float)v0[3] + (float)v1[3];
    *(float4*)(out + i) = o;
}

extern "C" void kernel_launch(void* const* d_in, const int* in_sizes, int n_in,
                              void* d_out, int out_size, void* d_ws, size_t ws_size,
                              hipStream_t stream)
{
    const float* X   = (const float*)d_in[0];
    const float* Y   = (const float*)d_in[1];
    const float* Wxq = (const float*)d_in[2];
    const float* bxq = (const float*)d_in[3];
    const float* Wyq = (const float*)d_in[4];
    const float* byq = (const float*)d_in[5];
    const float* Wfk = (const float*)d_in[6];
    const float* bfk = (const float*)d_in[7];
    const float* Wfv = (const float*)d_in[8];
    const float* bfv = (const float*)d_in[9];
    float* out = (float*)d_out;
    char*  ws  = (char*)d_ws;

    // ws: Qcat 0-32M | Kf 32-48M (Yb alias) | Vt 48-64M |
    //     Wb 64-67M / attn0 64-80M | Xb / attn1 80-96M
    bf16_t* Qcat = (bf16_t*)(ws);
    bf16_t* Kf   = (bf16_t*)(ws + (size_t)33554432);
    bf16_t* Vt   = (bf16_t*)(ws + (size_t)50331648);
    bf16_t* Wb   = (bf16_t*)(ws + (size_t)67108864);  // dead after k2
    bf16_t* attn = (bf16_t*)(ws + (size_t)67108864);  // attn0 @64M, attn1 @80M
    bf16_t* Xb   = (bf16_t*)(ws + (size_t)83886080);  // dead after k1
    bf16_t* Yb   = Kf;                                // dead before k2 writes Kf
    const bool big = ws_size >= (size_t)100663296;

    if (big) {
        k_cvt<<<dim3(2048), 256, 0, stream>>>(X, Y, Wxq, Wyq, Wfk, Wfv, Xb, Yb, Wb);
        k_qgemm_bb<<<dim3(8, 128), 256, 0, stream>>>(Xb, Yb, Wb, bxq, byq, Qcat);
        k_kvgemm_bb<<<dim3(8, 128), 256, 0, stream>>>(Qcat, Wb + 524288, bfk,
                                                      Wb + 1048576, bfv, Kf, Vt);
        k_attn<<<dim3(32, 8, 2), 256, 0, stream>>>(Qcat, Kf, Vt, X, Y, out, attn, 0, 0);
        k_add<<<dim3(8192), 256, 0, stream>>>(X, Y, attn, attn + (size_t)M_TOT * 512, out);
    } else {
        k_qgemm<<<dim3(128, 8), 256, 0, stream>>>(X, Y, Wxq, bxq, Wyq, byq, Qcat);
        k_kvgemm<<<dim3(128, 8), 256, 0, stream>>>(Qcat, Wfk, bfk, Wfv, bfv, Kf, Vt);
        k_attn<<<dim3(32, 8, 1), 256, 0, stream>>>(Qcat, Kf, Vt, X, Y, out, attn, 1, 0);
        k_attn<<<dim3(32, 8, 1), 256, 0, stream>>>(Qcat, Kf, Vt, X, Y, out, attn, 2, 1);
    }
}